// Round 2
// baseline (4059.290 us; speedup 1.0000x reference)
//
#include <hip/hip_runtime.h>
#include <hip/hip_bf16.h>
#include <cmath>

// Problem constants (match reference setup_inputs)
#define NN    50000
#define EE    1600000
#define FIN   512
#define NHEAD 8
#define OUT1  8
#define HID   64      // NHEAD*OUT1
#define NCLS  7

// ---------------------------------------------------------------------------
// Workspace layout (floats):
//   xh      @ 0          N*64
//   --- zero block start ---
//   D       @ 3,200,000  N
//   B       @ 3,250,000  N
//   den     @ 3,300,000  N*8
//   acc_e   @ 3,700,000  N*64
//   acc_n   @ 6,900,000  N*64
//   acc_e2  @ 10,100,000 N*8
//   acc_n2  @ 10,500,000 N*8
//   --- zero block end (7,700,000 floats) ---
//   s_i     @ 10,900,000 N*8
//   s_j     @ 11,300,000 N*8
//   h       @ 11,700,000 N*64
//   xh2     @ 14,900,000 N*8
//   total 15,300,000 floats = 61.2 MB
// ---------------------------------------------------------------------------
#define OFF_XH     0
#define OFF_D      3200000
#define OFF_B      3250000
#define OFF_DEN    3300000
#define OFF_ACCE   3700000
#define OFF_ACCN   6900000
#define OFF_ACCE2  10100000
#define OFF_ACCN2  10500000
#define OFF_SI     10900000
#define OFF_SJ     11300000
#define OFF_H      11700000
#define OFF_XH2    14900000
#define ZERO_FLOATS 7700000

// ---------------------------------------------------------------------------
// Zero the accumulator block (kernel, not hipMemsetAsync, to keep the graph
// node set minimal while we debug infra).  float4 grid-stride.
__global__ __launch_bounds__(256) void zero_kernel(float4* __restrict__ p, int n4) {
  int i = blockIdx.x * 256 + threadIdx.x;
  int stride = gridDim.x * 256;
  float4 z = make_float4(0.f, 0.f, 0.f, 0.f);
  for (; i < n4; i += stride) p[i] = z;
}

// ---------------------------------------------------------------------------
// Degree sums: D[n] = sum over edges with row==n of hw[col]; B[m] = #edges col==m
__global__ __launch_bounds__(256) void deg_kernel(const int* __restrict__ ei,
                                                  const float* __restrict__ hw,
                                                  float* __restrict__ D,
                                                  float* __restrict__ B) {
  int e = blockIdx.x * 256 + threadIdx.x;
  if (e >= EE) return;
  int r = ei[e];
  int c = ei[EE + e];
  atomicAdd(D + r, hw[c]);
  atomicAdd(B + c, 1.0f);
}

// ---------------------------------------------------------------------------
// GEMM1: xh[N,64] = x[N,512] @ W1[512,64].  64x64 block tile, BK=32,
// 256 threads, 4x4 microtile per thread, LDS-staged with transposed x tile.
__global__ __launch_bounds__(256) void gemm1_kernel(const float* __restrict__ x,
                                                    const float* __restrict__ W1,
                                                    float* __restrict__ xh) {
  __shared__ float lx[32][68];  // [kk][row]   (+pad to de-conflict)
  __shared__ float lw[32][68];  // [kk][col]
  const int t = threadIdx.x;
  const int row0 = blockIdx.x * 64;
  const int ty = t >> 4, tx = t & 15;
  const int r0 = ty * 4, c0 = tx * 4;
  float acc[4][4] = {};

  for (int kb = 0; kb < FIN; kb += 32) {
    // stage x tile (transposed): thread t loads row lr, 8 consecutive k
    {
      int lr = t >> 2;
      int lk = (t & 3) * 8;
      int grow = row0 + lr;
      float4 a0, a1;
      if (grow < NN) {
        const float4* p = reinterpret_cast<const float4*>(x + (size_t)grow * FIN + kb + lk);
        a0 = p[0]; a1 = p[1];
      } else {
        a0 = make_float4(0.f, 0.f, 0.f, 0.f); a1 = a0;
      }
      lx[lk + 0][lr] = a0.x; lx[lk + 1][lr] = a0.y;
      lx[lk + 2][lr] = a0.z; lx[lk + 3][lr] = a0.w;
      lx[lk + 4][lr] = a1.x; lx[lk + 5][lr] = a1.y;
      lx[lk + 6][lr] = a1.z; lx[lk + 7][lr] = a1.w;
    }
    // stage W tile: thread t loads k-row wk, 8 consecutive cols
    {
      int wk = t >> 3;
      int wc = (t & 7) * 8;
      const float4* q = reinterpret_cast<const float4*>(W1 + (size_t)(kb + wk) * HID + wc);
      float4 b0 = q[0], b1v = q[1];
      *reinterpret_cast<float4*>(&lw[wk][wc]) = b0;
      *reinterpret_cast<float4*>(&lw[wk][wc + 4]) = b1v;
    }
    __syncthreads();
#pragma unroll
    for (int kk = 0; kk < 32; ++kk) {
      const float4 af = *reinterpret_cast<const float4*>(&lx[kk][r0]);
      const float4 bf = *reinterpret_cast<const float4*>(&lw[kk][c0]);
      const float a4[4] = {af.x, af.y, af.z, af.w};
      const float b4[4] = {bf.x, bf.y, bf.z, bf.w};
#pragma unroll
      for (int i = 0; i < 4; ++i)
#pragma unroll
        for (int j = 0; j < 4; ++j)
          acc[i][j] = fmaf(a4[i], b4[j], acc[i][j]);
    }
    __syncthreads();
  }
#pragma unroll
  for (int i = 0; i < 4; ++i) {
    int gr = row0 + r0 + i;
    if (gr < NN) {
      float4 v = make_float4(acc[i][0], acc[i][1], acc[i][2], acc[i][3]);
      *reinterpret_cast<float4*>(xh + (size_t)gr * HID + c0) = v;
    }
  }
}

// ---------------------------------------------------------------------------
// Attention projections: s_i[n,h] = sum_c xh[n,h,c]*att1[h,c]; s_j with att1[h,8+c]
__global__ __launch_bounds__(256) void attscore_kernel(const float* __restrict__ xh,
                                                       const float* __restrict__ att1,
                                                       float* __restrict__ s_i,
                                                       float* __restrict__ s_j) {
  int t = blockIdx.x * 256 + threadIdx.x;
  if (t >= NN * NHEAD) return;
  int n = t >> 3, hh = t & 7;
  const float* xp = xh + (size_t)n * HID + hh * OUT1;
  float si = 0.f, sj = 0.f;
#pragma unroll
  for (int c = 0; c < OUT1; ++c) {
    float v = xp[c];
    si = fmaf(v, att1[hh * 16 + c], si);
    sj = fmaf(v, att1[hh * 16 + 8 + c], sj);
  }
  s_i[t] = si;
  s_j[t] = sj;
}

// ---------------------------------------------------------------------------
// Softmax denominator per (row, head).  Segment-max is skipped: scores are
// O(1) (att ~0.1 scale), exp cannot overflow, and softmax is shift-invariant.
__global__ __launch_bounds__(256) void den_kernel(const int* __restrict__ ei,
                                                  const float* __restrict__ s_i,
                                                  const float* __restrict__ s_j,
                                                  float* __restrict__ den) {
  int t = blockIdx.x * 256 + threadIdx.x;  // e*8 + h, exact grid
  int e = t >> 3, hh = t & 7;
  int r = ei[e], c = ei[EE + e];
  float a = s_i[r * 8 + hh] + s_j[c * 8 + hh];
  a = a > 0.f ? a : 0.2f * a;
  atomicAdd(den + r * 8 + hh, expf(a));
}

// ---------------------------------------------------------------------------
// Propagate 1 (nodes -> hyperedges): acc_e[col] += xh[row] * alpha
// 16 lanes per edge, one float4 each.  Binv factored out (applied in prop2).
__global__ __launch_bounds__(256) void prop1_kernel(const int* __restrict__ ei,
                                                    const float* __restrict__ s_i,
                                                    const float* __restrict__ s_j,
                                                    const float* __restrict__ den,
                                                    const float* __restrict__ xh,
                                                    float* __restrict__ acc_e) {
  int t = blockIdx.x * 256 + threadIdx.x;  // e*16 + q, exact grid
  int e = t >> 4, q = t & 15, hh = q >> 1;
  int r = ei[e], c = ei[EE + e];
  float a = s_i[r * 8 + hh] + s_j[c * 8 + hh];
  a = a > 0.f ? a : 0.2f * a;
  float alpha = expf(a) / (den[r * 8 + hh] + 1e-16f);
  float4 v = *reinterpret_cast<const float4*>(xh + (size_t)r * HID + q * 4);
  float* dst = acc_e + (size_t)c * HID + q * 4;
  atomicAdd(dst + 0, v.x * alpha);
  atomicAdd(dst + 1, v.y * alpha);
  atomicAdd(dst + 2, v.z * alpha);
  atomicAdd(dst + 3, v.w * alpha);
}

// ---------------------------------------------------------------------------
// Propagate 2 (hyperedges -> nodes): acc_n[row] += acc_e[col]*Binv[col]*alpha
// Dinv factored out (applied in finish1).
__global__ __launch_bounds__(256) void prop2_kernel(const int* __restrict__ ei,
                                                    const float* __restrict__ s_i,
                                                    const float* __restrict__ s_j,
                                                    const float* __restrict__ den,
                                                    const float* __restrict__ hw,
                                                    const float* __restrict__ B,
                                                    const float* __restrict__ acc_e,
                                                    float* __restrict__ acc_n) {
  int t = blockIdx.x * 256 + threadIdx.x;  // e*16 + q, exact grid
  int e = t >> 4, q = t & 15, hh = q >> 1;
  int r = ei[e], c = ei[EE + e];
  float a = s_i[r * 8 + hh] + s_j[c * 8 + hh];
  a = a > 0.f ? a : 0.2f * a;
  float alpha = expf(a) / (den[r * 8 + hh] + 1e-16f);
  float bv = B[c];
  float binv = bv > 0.f ? hw[c] / bv : 0.f;
  float s = binv * alpha;
  float4 v = *reinterpret_cast<const float4*>(acc_e + (size_t)c * HID + q * 4);
  float* dst = acc_n + (size_t)r * HID + q * 4;
  atomicAdd(dst + 0, v.x * s);
  atomicAdd(dst + 1, v.y * s);
  atomicAdd(dst + 2, v.z * s);
  atomicAdd(dst + 3, v.w * s);
}

// ---------------------------------------------------------------------------
// Epilogue layer 1: h = elu(acc_n * Dinv + b1)
__global__ __launch_bounds__(256) void finish1_kernel(const float* __restrict__ acc_n,
                                                      const float* __restrict__ D,
                                                      const float* __restrict__ b1,
                                                      float* __restrict__ h) {
  int t = blockIdx.x * 256 + threadIdx.x;  // n*64 + c, exact grid
  int n = t >> 6, c = t & 63;
  float d = D[n];
  float dinv = d > 0.f ? 1.0f / d : 0.f;
  float v = fmaf(acc_n[t], dinv, b1[c]);
  h[t] = v > 0.f ? v : expm1f(v);
}

// ---------------------------------------------------------------------------
// GEMM2: xh2[n,k] = sum_c h[n,c] * W2[c,k]   (k<7; slot 7 zero-filled)
__global__ __launch_bounds__(256) void gemm2_kernel(const float* __restrict__ h,
                                                    const float* __restrict__ W2,
                                                    float* __restrict__ xh2) {
  int t = blockIdx.x * 256 + threadIdx.x;
  if (t >= NN * 8) return;
  int n = t >> 3, k = t & 7;
  if (k == 7) { xh2[t] = 0.f; return; }
  const float* hp = h + (size_t)n * HID;
  float acc = 0.f;
#pragma unroll
  for (int c = 0; c < HID; ++c) acc = fmaf(hp[c], W2[c * NCLS + k], acc);
  xh2[t] = acc;
}

// ---------------------------------------------------------------------------
// Layer-2 propagate 1: acc_e2[col,k] += xh2[row,k]
__global__ __launch_bounds__(256) void prop3_kernel(const int* __restrict__ ei,
                                                    const float* __restrict__ xh2,
                                                    float* __restrict__ acc_e2) {
  int e = blockIdx.x * 256 + threadIdx.x;  // exact grid
  int r = ei[e], c = ei[EE + e];
  const float* src = xh2 + (size_t)r * 8;
  float* dst = acc_e2 + (size_t)c * 8;
#pragma unroll
  for (int k = 0; k < NCLS; ++k) atomicAdd(dst + k, src[k]);
}

// ---------------------------------------------------------------------------
// Layer-2 propagate 2: acc_n2[row,k] += acc_e2[col,k]*Binv[col]
__global__ __launch_bounds__(256) void prop4_kernel(const int* __restrict__ ei,
                                                    const float* __restrict__ hw,
                                                    const float* __restrict__ B,
                                                    const float* __restrict__ acc_e2,
                                                    float* __restrict__ acc_n2) {
  int e = blockIdx.x * 256 + threadIdx.x;  // exact grid
  int r = ei[e], c = ei[EE + e];
  float bv = B[c];
  float binv = bv > 0.f ? hw[c] / bv : 0.f;
  const float* src = acc_e2 + (size_t)c * 8;
  float* dst = acc_n2 + (size_t)r * 8;
#pragma unroll
  for (int k = 0; k < NCLS; ++k) atomicAdd(dst + k, src[k] * binv);
}

// ---------------------------------------------------------------------------
// Epilogue layer 2: out = log_softmax(acc_n2 * Dinv + b2)
__global__ __launch_bounds__(256) void finish2_kernel(const float* __restrict__ acc_n2,
                                                      const float* __restrict__ D,
                                                      const float* __restrict__ b2,
                                                      float* __restrict__ out) {
  int n = blockIdx.x * 256 + threadIdx.x;
  if (n >= NN) return;
  float d = D[n];
  float dinv = d > 0.f ? 1.0f / d : 0.f;
  float v[NCLS];
  float m = -INFINITY;
#pragma unroll
  for (int k = 0; k < NCLS; ++k) {
    v[k] = fmaf(acc_n2[(size_t)n * 8 + k], dinv, b2[k]);
    m = fmaxf(m, v[k]);
  }
  float s = 0.f;
#pragma unroll
  for (int k = 0; k < NCLS; ++k) s += expf(v[k] - m);
  float lse = m + logf(s);
#pragma unroll
  for (int k = 0; k < NCLS; ++k) out[(size_t)n * NCLS + k] = v[k] - lse;
}

// ---------------------------------------------------------------------------
extern "C" void kernel_launch(void* const* d_in, const int* in_sizes, int n_in,
                              void* d_out, int out_size, void* d_ws, size_t ws_size,
                              hipStream_t stream) {
  const float* x    = (const float*)d_in[0];
  const int*   ei   = (const int*)d_in[1];
  const float* hw   = (const float*)d_in[2];
  const float* W1   = (const float*)d_in[3];
  const float* att1 = (const float*)d_in[4];
  const float* b1   = (const float*)d_in[5];
  const float* W2   = (const float*)d_in[6];
  const float* b2   = (const float*)d_in[7];
  float* out = (float*)d_out;
  float* ws  = (float*)d_ws;

  float* xh     = ws + OFF_XH;
  float* Dd     = ws + OFF_D;
  float* Bd     = ws + OFF_B;
  float* den    = ws + OFF_DEN;
  float* acc_e  = ws + OFF_ACCE;
  float* acc_n  = ws + OFF_ACCN;
  float* acc_e2 = ws + OFF_ACCE2;
  float* acc_n2 = ws + OFF_ACCN2;
  float* s_i    = ws + OFF_SI;
  float* s_j    = ws + OFF_SJ;
  float* hbuf   = ws + OFF_H;
  float* xh2    = ws + OFF_XH2;

  // Zero all accumulators (contiguous block) every call — ws is not re-poisoned
  // between replays, so this must be unconditional and deterministic.
  zero_kernel<<<2048, 256, 0, stream>>>(reinterpret_cast<float4*>(Dd), ZERO_FLOATS / 4);

  deg_kernel<<<EE / 256, 256, 0, stream>>>(ei, hw, Dd, Bd);
  gemm1_kernel<<<(NN + 63) / 64, 256, 0, stream>>>(x, W1, xh);
  attscore_kernel<<<(NN * NHEAD + 255) / 256, 256, 0, stream>>>(xh, att1, s_i, s_j);
  den_kernel<<<EE * 8 / 256, 256, 0, stream>>>(ei, s_i, s_j, den);
  prop1_kernel<<<EE * 16 / 256, 256, 0, stream>>>(ei, s_i, s_j, den, xh, acc_e);
  prop2_kernel<<<EE * 16 / 256, 256, 0, stream>>>(ei, s_i, s_j, den, hw, Bd, acc_e, acc_n);
  finish1_kernel<<<NN * HID / 256, 256, 0, stream>>>(acc_n, Dd, b1, hbuf);
  gemm2_kernel<<<(NN * 8 + 255) / 256, 256, 0, stream>>>(hbuf, W2, xh2);
  prop3_kernel<<<EE / 256, 256, 0, stream>>>(ei, xh2, acc_e2);
  prop4_kernel<<<EE / 256, 256, 0, stream>>>(ei, hw, Bd, acc_e2, acc_n2);
  finish2_kernel<<<(NN + 255) / 256, 256, 0, stream>>>(acc_n2, Dd, b2, out);
}

// Round 3
// 1004.480 us; speedup vs baseline: 4.0412x; 4.0412x over previous
//
#include <hip/hip_runtime.h>
#include <hip/hip_bf16.h>
#include <cmath>

// Problem constants (match reference setup_inputs)
#define NN    50000
#define EE    1600000
#define FIN   512
#define NHEAD 8
#define OUT1  8
#define HID   64      // NHEAD*OUT1
#define NCLS  7

// ---------------------------------------------------------------------------
// Workspace layout (4-byte elements):
//   xh      @ 0          N*64   f32
//   s_i     @ 3,200,000  N*8
//   s_j     @ 3,600,000  N*8
//   rden    @ 4,000,000  N*8    (reciprocal of softmax denominator)
//   Binv    @ 4,400,000  N      (hw/B)
//   acc_e   @ 4,450,000  N*64
//   h       @ 7,650,000  N*64
//   xh2     @ 10,850,000 N*8
//   acc_e2  @ 11,250,000 N*8
//   rhist   @ 11,650,000 N      int   -- zeroed each call
//   chist   @ 11,700,000 N      int   -- zeroed each call (contiguous w/ rhist)
//   rptr    @ 11,750,000 N+1    int
//   cptr    @ 11,800,001 N+1    int
//   rcur    @ 11,850,002 N      int
//   ccur    @ 11,900,002 N      int
//   csr_row_c @ 11,950,002 E    int   (col endpoint, grouped by row)
//   csr_col_r @ 13,550,002 E    int   (row endpoint, grouped by col)
//   total 15,150,002 elems = 60.6 MB
// ---------------------------------------------------------------------------
#define OFF_XH     0
#define OFF_SI     3200000
#define OFF_SJ     3600000
#define OFF_RDEN   4000000
#define OFF_BINV   4400000
#define OFF_ACCE   4450000
#define OFF_H      7650000
#define OFF_XH2    10850000
#define OFF_ACCE2  11250000
#define OFF_RHIST  11650000
#define OFF_CHIST  11700000
#define OFF_RPTR   11750000
#define OFF_CPTR   11800001
#define OFF_RCUR   11850002
#define OFF_CCUR   11900002
#define OFF_CSRRC  11950002
#define OFF_CSRCR  13550002

// ---------------------------------------------------------------------------
__global__ __launch_bounds__(256) void zero_kernel(int* __restrict__ p, int n) {
  int i = blockIdx.x * 256 + threadIdx.x;
  if (i < n) p[i] = 0;
}

// ---------------------------------------------------------------------------
// Histogram of rows and cols (int atomics into L2-resident 200KB tables).
__global__ __launch_bounds__(256) void hist_kernel(const int* __restrict__ ei,
                                                   int* __restrict__ rhist,
                                                   int* __restrict__ chist) {
  int e = blockIdx.x * 256 + threadIdx.x;
  if (e >= EE) return;
  atomicAdd(rhist + ei[e], 1);
  atomicAdd(chist + ei[EE + e], 1);
}

// ---------------------------------------------------------------------------
// Exclusive scan of one N-length histogram into an (N+1)-length ptr array.
// blockIdx.x 0 -> row, 1 -> col (hist arrays contiguous, ptr arrays contiguous).
__global__ __launch_bounds__(1024) void scan_kernel(const int* __restrict__ hist0,
                                                    int* __restrict__ ptr0) {
  const int n = NN;
  const int* hist = hist0 + blockIdx.x * NN;
  int* ptr = ptr0 + blockIdx.x * (NN + 1);
  __shared__ int lds[1024];
  __shared__ int carry_s;
  if (threadIdx.x == 0) carry_s = 0;
  __syncthreads();
  for (int base = 0; base < n; base += 1024) {
    int i = base + threadIdx.x;
    int v = (i < n) ? hist[i] : 0;
    lds[threadIdx.x] = v;
    __syncthreads();
    int carry = carry_s;
#pragma unroll
    for (int off = 1; off < 1024; off <<= 1) {
      int t = (threadIdx.x >= off) ? lds[threadIdx.x - off] : 0;
      __syncthreads();
      lds[threadIdx.x] += t;
      __syncthreads();
    }
    int incl = lds[threadIdx.x];
    int total = lds[1023];
    if (i < n) ptr[i] = carry + incl - v;
    __syncthreads();
    if (threadIdx.x == 0) carry_s = carry + total;
    __syncthreads();
  }
  if (threadIdx.x == 0) ptr[n] = carry_s;
}

// ---------------------------------------------------------------------------
// Copy scatter cursors; compute Binv = hw/B (B = col count).
__global__ __launch_bounds__(256) void prep_kernel(const int* __restrict__ rptr,
                                                   const int* __restrict__ cptr,
                                                   const int* __restrict__ chist,
                                                   const float* __restrict__ hw,
                                                   int* __restrict__ rcur,
                                                   int* __restrict__ ccur,
                                                   float* __restrict__ Binv) {
  int i = blockIdx.x * 256 + threadIdx.x;
  if (i >= NN) return;
  rcur[i] = rptr[i];
  ccur[i] = cptr[i];
  int bc = chist[i];
  Binv[i] = bc > 0 ? hw[i] / (float)bc : 0.f;
}

// ---------------------------------------------------------------------------
// Scatter edges into both CSR orderings (stores the OTHER endpoint).
__global__ __launch_bounds__(256) void scatter_kernel(const int* __restrict__ ei,
                                                      int* __restrict__ rcur,
                                                      int* __restrict__ ccur,
                                                      int* __restrict__ csr_row_c,
                                                      int* __restrict__ csr_col_r) {
  int e = blockIdx.x * 256 + threadIdx.x;
  if (e >= EE) return;
  int r = ei[e], c = ei[EE + e];
  int pr = atomicAdd(rcur + r, 1);
  csr_row_c[pr] = c;
  int pc = atomicAdd(ccur + c, 1);
  csr_col_r[pc] = r;
}

// ---------------------------------------------------------------------------
// GEMM1: xh[N,64] = x[N,512] @ W1[512,64].  64x64 tile, BK=32, 4x4 microtile.
__global__ __launch_bounds__(256) void gemm1_kernel(const float* __restrict__ x,
                                                    const float* __restrict__ W1,
                                                    float* __restrict__ xh) {
  __shared__ float lx[32][68];
  __shared__ float lw[32][68];
  const int t = threadIdx.x;
  const int row0 = blockIdx.x * 64;
  const int ty = t >> 4, tx = t & 15;
  const int r0 = ty * 4, c0 = tx * 4;
  float acc[4][4] = {};

  for (int kb = 0; kb < FIN; kb += 32) {
    {
      int lr = t >> 2;
      int lk = (t & 3) * 8;
      int grow = row0 + lr;
      float4 a0, a1;
      if (grow < NN) {
        const float4* p = reinterpret_cast<const float4*>(x + (size_t)grow * FIN + kb + lk);
        a0 = p[0]; a1 = p[1];
      } else {
        a0 = make_float4(0.f, 0.f, 0.f, 0.f); a1 = a0;
      }
      lx[lk + 0][lr] = a0.x; lx[lk + 1][lr] = a0.y;
      lx[lk + 2][lr] = a0.z; lx[lk + 3][lr] = a0.w;
      lx[lk + 4][lr] = a1.x; lx[lk + 5][lr] = a1.y;
      lx[lk + 6][lr] = a1.z; lx[lk + 7][lr] = a1.w;
    }
    {
      int wk = t >> 3;
      int wc = (t & 7) * 8;
      const float4* q = reinterpret_cast<const float4*>(W1 + (size_t)(kb + wk) * HID + wc);
      float4 b0 = q[0], b1v = q[1];
      *reinterpret_cast<float4*>(&lw[wk][wc]) = b0;
      *reinterpret_cast<float4*>(&lw[wk][wc + 4]) = b1v;
    }
    __syncthreads();
#pragma unroll
    for (int kk = 0; kk < 32; ++kk) {
      const float4 af = *reinterpret_cast<const float4*>(&lx[kk][r0]);
      const float4 bf = *reinterpret_cast<const float4*>(&lw[kk][c0]);
      const float a4[4] = {af.x, af.y, af.z, af.w};
      const float b4[4] = {bf.x, bf.y, bf.z, bf.w};
#pragma unroll
      for (int i = 0; i < 4; ++i)
#pragma unroll
        for (int j = 0; j < 4; ++j)
          acc[i][j] = fmaf(a4[i], b4[j], acc[i][j]);
    }
    __syncthreads();
  }
#pragma unroll
  for (int i = 0; i < 4; ++i) {
    int gr = row0 + r0 + i;
    if (gr < NN) {
      float4 v = make_float4(acc[i][0], acc[i][1], acc[i][2], acc[i][3]);
      *reinterpret_cast<float4*>(xh + (size_t)gr * HID + c0) = v;
    }
  }
}

// ---------------------------------------------------------------------------
// Attention projections: s_i[n,h], s_j[n,h]
__global__ __launch_bounds__(256) void attscore_kernel(const float* __restrict__ xh,
                                                       const float* __restrict__ att1,
                                                       float* __restrict__ s_i,
                                                       float* __restrict__ s_j) {
  int t = blockIdx.x * 256 + threadIdx.x;
  if (t >= NN * NHEAD) return;
  int n = t >> 3, hh = t & 7;
  const float* xp = xh + (size_t)n * HID + hh * OUT1;
  float si = 0.f, sj = 0.f;
#pragma unroll
  for (int c = 0; c < OUT1; ++c) {
    float v = xp[c];
    si = fmaf(v, att1[hh * 16 + c], si);
    sj = fmaf(v, att1[hh * 16 + 8 + c], sj);
  }
  s_i[t] = si;
  s_j[t] = sj;
}

// ---------------------------------------------------------------------------
// Softmax denominator per (row, head): wave per node, lanes = [8 eslots][8 heads].
// Stores the RECIPROCAL.  Segment-max skipped (scores O(1); shift-invariant).
__global__ __launch_bounds__(256) void den_csr(const int* __restrict__ rptr,
                                               const int* __restrict__ csr_row_c,
                                               const float* __restrict__ s_i,
                                               const float* __restrict__ s_j,
                                               float* __restrict__ rden) {
  int wid = (blockIdx.x * 256 + threadIdx.x) >> 6;
  int lane = threadIdx.x & 63;
  if (wid >= NN) return;
  int r = wid;
  int hh = lane & 7;
  int eslot = lane >> 3;
  float si = s_i[r * 8 + hh];
  int beg = rptr[r], end = rptr[r + 1];
  float acc = 0.f;
  for (int i = beg + eslot; i < end; i += 8) {
    int c = csr_row_c[i];
    float a = si + s_j[c * 8 + hh];
    a = a > 0.f ? a : 0.2f * a;
    acc += expf(a);
  }
  acc += __shfl_xor(acc, 8);
  acc += __shfl_xor(acc, 16);
  acc += __shfl_xor(acc, 32);
  if (eslot == 0) rden[r * 8 + hh] = 1.0f / (acc + 1e-16f);
}

// ---------------------------------------------------------------------------
// Propagate 1 (nodes -> hyperedges), gather form: wave per hyperedge c,
// lane = channel.  acc_e[c] = sum_r alpha * xh[r].  (Binv applied in prop2.)
__global__ __launch_bounds__(256) void prop1_csr(const int* __restrict__ cptr,
                                                 const int* __restrict__ csr_col_r,
                                                 const float* __restrict__ xh,
                                                 const float* __restrict__ s_i,
                                                 const float* __restrict__ s_j,
                                                 const float* __restrict__ rden,
                                                 float* __restrict__ acc_e) {
  int wid = (blockIdx.x * 256 + threadIdx.x) >> 6;
  int lane = threadIdx.x & 63;
  if (wid >= NN) return;
  int c = wid;
  int hh = lane >> 3;
  float sj = s_j[c * 8 + hh];
  int beg = cptr[c], end = cptr[c + 1];
  float acc = 0.f;
  for (int i = beg; i < end; ++i) {
    int r = csr_col_r[i];
    float a = s_i[r * 8 + hh] + sj;
    a = a > 0.f ? a : 0.2f * a;
    float alpha = expf(a) * rden[r * 8 + hh];
    acc += xh[(size_t)r * HID + lane] * alpha;
  }
  acc_e[(size_t)c * HID + lane] = acc;
}

// ---------------------------------------------------------------------------
// Propagate 2 (hyperedges -> nodes) + finish1 fused: wave per node r.
// h[r] = elu(Dinv * sum_c alpha*Binv[c]*acc_e[c] + b1).  D computed in-loop.
__global__ __launch_bounds__(256) void prop2_csr(const int* __restrict__ rptr,
                                                 const int* __restrict__ csr_row_c,
                                                 const float* __restrict__ acc_e,
                                                 const float* __restrict__ s_i,
                                                 const float* __restrict__ s_j,
                                                 const float* __restrict__ rden,
                                                 const float* __restrict__ Binv,
                                                 const float* __restrict__ hw,
                                                 const float* __restrict__ b1,
                                                 float* __restrict__ h) {
  int wid = (blockIdx.x * 256 + threadIdx.x) >> 6;
  int lane = threadIdx.x & 63;
  if (wid >= NN) return;
  int r = wid;
  int hh = lane >> 3;
  float si = s_i[r * 8 + hh];
  float rd = rden[r * 8 + hh];
  int beg = rptr[r], end = rptr[r + 1];
  float acc = 0.f, dsum = 0.f;
  for (int i = beg; i < end; ++i) {
    int c = csr_row_c[i];
    float a = si + s_j[c * 8 + hh];
    a = a > 0.f ? a : 0.2f * a;
    float alpha = expf(a) * rd;
    acc += acc_e[(size_t)c * HID + lane] * (Binv[c] * alpha);
    dsum += hw[c];
  }
  float dinv = dsum > 0.f ? 1.0f / dsum : 0.f;
  float v = fmaf(acc, dinv, b1[lane]);
  h[(size_t)r * HID + lane] = v > 0.f ? v : expm1f(v);
}

// ---------------------------------------------------------------------------
// GEMM2: xh2[n,k] = sum_c h[n,c]*W2[c,k]  (k<7; slot 7 zeroed)
__global__ __launch_bounds__(256) void gemm2_kernel(const float* __restrict__ h,
                                                    const float* __restrict__ W2,
                                                    float* __restrict__ xh2) {
  int t = blockIdx.x * 256 + threadIdx.x;
  if (t >= NN * 8) return;
  int n = t >> 3, k = t & 7;
  if (k == 7) { xh2[t] = 0.f; return; }
  const float* hp = h + (size_t)n * HID;
  float acc = 0.f;
#pragma unroll
  for (int c = 0; c < HID; ++c) acc = fmaf(hp[c], W2[c * NCLS + k], acc);
  xh2[t] = acc;
}

// ---------------------------------------------------------------------------
// Layer-2 propagate 1, gather form: 8 lanes per hyperedge.
__global__ __launch_bounds__(256) void prop3_csr(const int* __restrict__ cptr,
                                                 const int* __restrict__ csr_col_r,
                                                 const float* __restrict__ xh2,
                                                 float* __restrict__ acc_e2) {
  int t = blockIdx.x * 256 + threadIdx.x;
  int g = t >> 3, k = t & 7;
  if (g >= NN) return;
  int beg = cptr[g], end = cptr[g + 1];
  float acc = 0.f;
  for (int i = beg; i < end; ++i) {
    int r = csr_col_r[i];
    acc += xh2[(size_t)r * 8 + k];
  }
  acc_e2[(size_t)g * 8 + k] = acc;
}

// ---------------------------------------------------------------------------
// Layer-2 propagate 2 + log_softmax fused: 8 lanes per node.
__global__ __launch_bounds__(256) void prop4_csr(const int* __restrict__ rptr,
                                                 const int* __restrict__ csr_row_c,
                                                 const float* __restrict__ acc_e2,
                                                 const float* __restrict__ Binv,
                                                 const float* __restrict__ hw,
                                                 const float* __restrict__ b2,
                                                 float* __restrict__ out) {
  int t = blockIdx.x * 256 + threadIdx.x;
  int r = t >> 3, k = t & 7;
  if (r >= NN) return;
  int beg = rptr[r], end = rptr[r + 1];
  float acc = 0.f, dsum = 0.f;
  for (int i = beg; i < end; ++i) {
    int c = csr_row_c[i];
    acc += acc_e2[(size_t)c * 8 + k] * Binv[c];
    dsum += hw[c];
  }
  float dinv = dsum > 0.f ? 1.0f / dsum : 0.f;
  float v = (k < NCLS) ? fmaf(acc, dinv, b2[k]) : -INFINITY;
  float m = v;
  m = fmaxf(m, __shfl_xor(m, 1, 8));
  m = fmaxf(m, __shfl_xor(m, 2, 8));
  m = fmaxf(m, __shfl_xor(m, 4, 8));
  float ex = (k < NCLS) ? expf(v - m) : 0.f;
  float s = ex;
  s += __shfl_xor(s, 1, 8);
  s += __shfl_xor(s, 2, 8);
  s += __shfl_xor(s, 4, 8);
  float lse = m + logf(s);
  if (k < NCLS) out[(size_t)r * NCLS + k] = v - lse;
}

// ---------------------------------------------------------------------------
extern "C" void kernel_launch(void* const* d_in, const int* in_sizes, int n_in,
                              void* d_out, int out_size, void* d_ws, size_t ws_size,
                              hipStream_t stream) {
  const float* x    = (const float*)d_in[0];
  const int*   ei   = (const int*)d_in[1];
  const float* hw   = (const float*)d_in[2];
  const float* W1   = (const float*)d_in[3];
  const float* att1 = (const float*)d_in[4];
  const float* b1   = (const float*)d_in[5];
  const float* W2   = (const float*)d_in[6];
  const float* b2   = (const float*)d_in[7];
  float* out = (float*)d_out;
  float* ws  = (float*)d_ws;

  float* xh     = ws + OFF_XH;
  float* s_i    = ws + OFF_SI;
  float* s_j    = ws + OFF_SJ;
  float* rden   = ws + OFF_RDEN;
  float* Binv   = ws + OFF_BINV;
  float* acc_e  = ws + OFF_ACCE;
  float* hbuf   = ws + OFF_H;
  float* xh2    = ws + OFF_XH2;
  float* acc_e2 = ws + OFF_ACCE2;
  int* rhist = (int*)(ws + OFF_RHIST);
  int* chist = (int*)(ws + OFF_CHIST);
  int* rptr  = (int*)(ws + OFF_RPTR);
  int* cptr  = (int*)(ws + OFF_CPTR);
  int* rcur  = (int*)(ws + OFF_RCUR);
  int* ccur  = (int*)(ws + OFF_CCUR);
  int* csr_row_c = (int*)(ws + OFF_CSRRC);
  int* csr_col_r = (int*)(ws + OFF_CSRCR);

  // --- CSR build ---
  zero_kernel<<<(2 * NN + 255) / 256, 256, 0, stream>>>(rhist, 2 * NN);
  hist_kernel<<<EE / 256, 256, 0, stream>>>(ei, rhist, chist);
  scan_kernel<<<2, 1024, 0, stream>>>(rhist, rptr);
  prep_kernel<<<(NN + 255) / 256, 256, 0, stream>>>(rptr, cptr, chist, hw, rcur, ccur, Binv);
  scatter_kernel<<<EE / 256, 256, 0, stream>>>(ei, rcur, ccur, csr_row_c, csr_col_r);

  // --- Layer 1 ---
  gemm1_kernel<<<(NN + 63) / 64, 256, 0, stream>>>(x, W1, xh);
  attscore_kernel<<<(NN * NHEAD + 255) / 256, 256, 0, stream>>>(xh, att1, s_i, s_j);
  den_csr<<<(NN * 64 + 255) / 256, 256, 0, stream>>>(rptr, csr_row_c, s_i, s_j, rden);
  prop1_csr<<<(NN * 64 + 255) / 256, 256, 0, stream>>>(cptr, csr_col_r, xh, s_i, s_j, rden, acc_e);
  prop2_csr<<<(NN * 64 + 255) / 256, 256, 0, stream>>>(rptr, csr_row_c, acc_e, s_i, s_j, rden,
                                                       Binv, hw, b1, hbuf);

  // --- Layer 2 ---
  gemm2_kernel<<<(NN * 8 + 255) / 256, 256, 0, stream>>>(hbuf, W2, xh2);
  prop3_csr<<<(NN * 8 + 255) / 256, 256, 0, stream>>>(cptr, csr_col_r, xh2, acc_e2);
  prop4_csr<<<(NN * 8 + 255) / 256, 256, 0, stream>>>(rptr, csr_row_c, acc_e2, Binv, hw, b2, out);
}

// Round 4
// 573.938 us; speedup vs baseline: 7.0727x; 1.7502x over previous
//
#include <hip/hip_runtime.h>
#include <hip/hip_bf16.h>
#include <cmath>

// Problem constants (match reference setup_inputs)
#define NN    50000
#define EE    1600000
#define FIN   512
#define NHEAD 8
#define OUT1  8
#define HID   64      // NHEAD*OUT1
#define NCLS  7

#define NB    391     // ceil(NN/128) buckets of 128 nodes
#define EPB   4096    // edges per block in phase A

// ---------------------------------------------------------------------------
// Workspace layout (4-byte elements):
//   xh      @ 0          N*64   (tmp_r aliases here during CSR build)
//   s_i     @ 3,200,000  N*8
//   s_j     @ 3,600,000  N*8
//   rden    @ 4,000,000  N*8
//   Binv    @ 4,400,000  N
//   acc_e   @ 4,450,000  N*64   (tmp_c aliases here during CSR build)
//   h       @ 7,650,000  N*64
//   xh2     @ 10,850,000 N*8
//   acc_e2  @ 11,250,000 N*8
//   rptr    @ 11,650,000 N+1  int
//   cptr    @ 11,701,000 N+1  int
//   bh_r    @ 11,760,000 NB+1 int  (zeroed each call)
//   bh_c    @ 11,761,000 NB+1 int  (zeroed each call)
//   bs_r    @ 11,762,000 NB+1 int
//   bs_c    @ 11,763,000 NB+1 int
//   bc_r    @ 11,764,000 NB+1 int
//   bc_c    @ 11,765,000 NB+1 int
//   csr_row_c @ 11,770,000 E  int
//   csr_col_r @ 13,370,000 E  int
//   total 14,970,000 elems = 59.9 MB
// ---------------------------------------------------------------------------
#define OFF_XH     0
#define OFF_SI     3200000
#define OFF_SJ     3600000
#define OFF_RDEN   4000000
#define OFF_BINV   4400000
#define OFF_ACCE   4450000
#define OFF_H      7650000
#define OFF_XH2    10850000
#define OFF_ACCE2  11250000
#define OFF_RPTR   11650000
#define OFF_CPTR   11701000
#define OFF_BHR    11760000
#define OFF_BHC    11761000
#define OFF_BSR    11762000
#define OFF_BSC    11763000
#define OFF_BCR    11764000
#define OFF_BCC    11765000
#define OFF_CSRRC  11770000
#define OFF_CSRCR  13370000

// ---------------------------------------------------------------------------
__global__ __launch_bounds__(512) void zero_small(int* __restrict__ bh_r,
                                                  int* __restrict__ bh_c) {
  int t = threadIdx.x;
  if (t <= NB) { bh_r[t] = 0; bh_c[t] = 0; }
}

// ---------------------------------------------------------------------------
// Coarse bucket histogram, privatized in LDS (NB counters per side).
__global__ __launch_bounds__(256) void bucket_hist(const int* __restrict__ ei,
                                                   int* __restrict__ bh_r,
                                                   int* __restrict__ bh_c) {
  __shared__ int hr[NB], hc[NB];
  int t = threadIdx.x;
  for (int i = t; i < NB; i += 256) { hr[i] = 0; hc[i] = 0; }
  __syncthreads();
  for (int i = blockIdx.x * 256 + t; i < EE; i += gridDim.x * 256) {
    atomicAdd(hr + (ei[i] >> 7), 1);
    atomicAdd(hc + (ei[EE + i] >> 7), 1);
  }
  __syncthreads();
  for (int i = t; i < NB; i += 256) {
    if (hr[i]) atomicAdd(bh_r + i, hr[i]);
    if (hc[i]) atomicAdd(bh_c + i, hc[i]);
  }
}

// ---------------------------------------------------------------------------
// Exclusive scan of the NB bucket histograms -> bucket starts + cursors.
__global__ __launch_bounds__(512) void bucket_scan(const int* __restrict__ bh_r,
                                                   const int* __restrict__ bh_c,
                                                   int* __restrict__ bs_r,
                                                   int* __restrict__ bs_c,
                                                   int* __restrict__ bc_r,
                                                   int* __restrict__ bc_c) {
  __shared__ int lds[512];
  int t = threadIdx.x;
  for (int side = 0; side < 2; ++side) {
    const int* bh = side ? bh_c : bh_r;
    int* bs = side ? bs_c : bs_r;
    int* bc = side ? bc_c : bc_r;
    int v = (t < NB) ? bh[t] : 0;
    lds[t] = v;
    __syncthreads();
    for (int off = 1; off < 512; off <<= 1) {
      int u = (t >= off) ? lds[t - off] : 0;
      __syncthreads();
      lds[t] += u;
      __syncthreads();
    }
    int excl = lds[t] - v;
    if (t <= NB) bs[t] = excl;
    if (t < NB) bc[t] = excl;
    __syncthreads();
  }
}

// ---------------------------------------------------------------------------
// Phase A: bucketed scatter with per-block privatized reservation.
// Emits packed ((own&127)<<16 | other) entries grouped by bucket.
__global__ __launch_bounds__(256) void phaseA(const int* __restrict__ ei,
                                              int* __restrict__ bc_r,
                                              int* __restrict__ bc_c,
                                              int* __restrict__ tmp_r,
                                              int* __restrict__ tmp_c) {
  __shared__ int er[EPB];
  __shared__ int ec[EPB];
  __shared__ int hr[NB], hc[NB];
  const int e0 = blockIdx.x * EPB;
  const int cntE = min(EPB, EE - e0);
  const int t = threadIdx.x;
  for (int i = t; i < cntE; i += 256) { er[i] = ei[e0 + i]; ec[i] = ei[EE + e0 + i]; }
  for (int i = t; i < NB; i += 256) { hr[i] = 0; hc[i] = 0; }
  __syncthreads();
  for (int i = t; i < cntE; i += 256) {
    atomicAdd(hr + (er[i] >> 7), 1);
    atomicAdd(hc + (ec[i] >> 7), 1);
  }
  __syncthreads();
  // reserve contiguous runs; hr/hc become running cursors
  for (int i = t; i < NB; i += 256) {
    int n = hr[i];
    hr[i] = n ? atomicAdd(bc_r + i, n) : 0;
    n = hc[i];
    hc[i] = n ? atomicAdd(bc_c + i, n) : 0;
  }
  __syncthreads();
  for (int i = t; i < cntE; i += 256) {
    int r = er[i], c = ec[i];
    int pr = atomicAdd(hr + (r >> 7), 1);
    tmp_r[pr] = ((r & 127) << 16) | c;
    int pc = atomicAdd(hc + (c >> 7), 1);
    tmp_c[pc] = ((c & 127) << 16) | r;
  }
}

// ---------------------------------------------------------------------------
// Phase B: one block per (side, bucket).  Builds the per-node layout in LDS,
// writes rptr/cptr (+Binv on the col side), and places the CSR entries.
__global__ __launch_bounds__(256) void phaseB(const int* __restrict__ tmp_r,
                                              const int* __restrict__ tmp_c,
                                              const int* __restrict__ bs_r,
                                              const int* __restrict__ bs_c,
                                              const float* __restrict__ hw,
                                              int* __restrict__ rptr,
                                              int* __restrict__ cptr,
                                              int* __restrict__ csr_row_c,
                                              int* __restrict__ csr_col_r,
                                              float* __restrict__ Binv) {
  const int side = blockIdx.x >= NB ? 1 : 0;
  const int b = blockIdx.x - side * NB;
  const int* tmp = side ? tmp_c : tmp_r;
  const int* bs = side ? bs_c : bs_r;
  int* ptr = side ? cptr : rptr;
  int* csr = side ? csr_col_r : csr_row_c;

  const int base = bs[b];
  const int M = bs[b + 1] - base;
  __shared__ int cnt[128], pre[128], cur[128];
  const int t = threadIdx.x;
  if (t < 128) cnt[t] = 0;
  __syncthreads();
  for (int i = t; i < M; i += 256) atomicAdd(cnt + (tmp[base + i] >> 16), 1);
  __syncthreads();
  if (t < 128) pre[t] = cnt[t];
  __syncthreads();
  for (int off = 1; off < 128; off <<= 1) {
    int u = (t >= off && t < 128) ? pre[t - off] : 0;
    __syncthreads();
    if (t < 128) pre[t] += u;
    __syncthreads();
  }
  const int node0 = b << 7;
  if (t < 128) {
    int excl = pre[t] - cnt[t];
    int g = node0 + t;
    if (g <= NN) ptr[g] = base + excl;
    cur[t] = base + excl;
    if (side && g < NN) Binv[g] = cnt[t] > 0 ? hw[g] / (float)cnt[t] : 0.f;
  }
  __syncthreads();
  for (int i = t; i < M; i += 256) {
    int e = tmp[base + i];
    int pos = atomicAdd(cur + (e >> 16), 1);
    csr[pos] = e & 0xFFFF;
  }
}

// ---------------------------------------------------------------------------
// GEMM1: xh[N,64] = x[N,512] @ W1[512,64].  64x64 tile, BK=32, 4x4 microtile.
__global__ __launch_bounds__(256) void gemm1_kernel(const float* __restrict__ x,
                                                    const float* __restrict__ W1,
                                                    float* __restrict__ xh) {
  __shared__ float lx[32][68];
  __shared__ float lw[32][68];
  const int t = threadIdx.x;
  const int row0 = blockIdx.x * 64;
  const int ty = t >> 4, tx = t & 15;
  const int r0 = ty * 4, c0 = tx * 4;
  float acc[4][4] = {};

  for (int kb = 0; kb < FIN; kb += 32) {
    {
      int lr = t >> 2;
      int lk = (t & 3) * 8;
      int grow = row0 + lr;
      float4 a0, a1;
      if (grow < NN) {
        const float4* p = reinterpret_cast<const float4*>(x + (size_t)grow * FIN + kb + lk);
        a0 = p[0]; a1 = p[1];
      } else {
        a0 = make_float4(0.f, 0.f, 0.f, 0.f); a1 = a0;
      }
      lx[lk + 0][lr] = a0.x; lx[lk + 1][lr] = a0.y;
      lx[lk + 2][lr] = a0.z; lx[lk + 3][lr] = a0.w;
      lx[lk + 4][lr] = a1.x; lx[lk + 5][lr] = a1.y;
      lx[lk + 6][lr] = a1.z; lx[lk + 7][lr] = a1.w;
    }
    {
      int wk = t >> 3;
      int wc = (t & 7) * 8;
      const float4* q = reinterpret_cast<const float4*>(W1 + (size_t)(kb + wk) * HID + wc);
      float4 b0 = q[0], b1v = q[1];
      *reinterpret_cast<float4*>(&lw[wk][wc]) = b0;
      *reinterpret_cast<float4*>(&lw[wk][wc + 4]) = b1v;
    }
    __syncthreads();
#pragma unroll
    for (int kk = 0; kk < 32; ++kk) {
      const float4 af = *reinterpret_cast<const float4*>(&lx[kk][r0]);
      const float4 bf = *reinterpret_cast<const float4*>(&lw[kk][c0]);
      const float a4[4] = {af.x, af.y, af.z, af.w};
      const float b4[4] = {bf.x, bf.y, bf.z, bf.w};
#pragma unroll
      for (int i = 0; i < 4; ++i)
#pragma unroll
        for (int j = 0; j < 4; ++j)
          acc[i][j] = fmaf(a4[i], b4[j], acc[i][j]);
    }
    __syncthreads();
  }
#pragma unroll
  for (int i = 0; i < 4; ++i) {
    int gr = row0 + r0 + i;
    if (gr < NN) {
      float4 v = make_float4(acc[i][0], acc[i][1], acc[i][2], acc[i][3]);
      *reinterpret_cast<float4*>(xh + (size_t)gr * HID + c0) = v;
    }
  }
}

// ---------------------------------------------------------------------------
// Attention projections: s_i[n,h], s_j[n,h]
__global__ __launch_bounds__(256) void attscore_kernel(const float* __restrict__ xh,
                                                       const float* __restrict__ att1,
                                                       float* __restrict__ s_i,
                                                       float* __restrict__ s_j) {
  int t = blockIdx.x * 256 + threadIdx.x;
  if (t >= NN * NHEAD) return;
  int n = t >> 3, hh = t & 7;
  const float* xp = xh + (size_t)n * HID + hh * OUT1;
  float si = 0.f, sj = 0.f;
#pragma unroll
  for (int c = 0; c < OUT1; ++c) {
    float v = xp[c];
    si = fmaf(v, att1[hh * 16 + c], si);
    sj = fmaf(v, att1[hh * 16 + 8 + c], sj);
  }
  s_i[t] = si;
  s_j[t] = sj;
}

// ---------------------------------------------------------------------------
// Softmax denominator per (row, head): wave per node, lanes = [8 eslots][8 heads].
// Stores the RECIPROCAL.  Segment-max skipped (scores O(1); shift-invariant).
__global__ __launch_bounds__(256) void den_csr(const int* __restrict__ rptr,
                                               const int* __restrict__ csr_row_c,
                                               const float* __restrict__ s_i,
                                               const float* __restrict__ s_j,
                                               float* __restrict__ rden) {
  int wid = (blockIdx.x * 256 + threadIdx.x) >> 6;
  int lane = threadIdx.x & 63;
  if (wid >= NN) return;
  int r = wid;
  int hh = lane & 7;
  int eslot = lane >> 3;
  float si = s_i[r * 8 + hh];
  int beg = rptr[r], end = rptr[r + 1];
  float acc = 0.f;
  for (int i = beg + eslot; i < end; i += 8) {
    int c = csr_row_c[i];
    float a = si + s_j[c * 8 + hh];
    a = a > 0.f ? a : 0.2f * a;
    acc += expf(a);
  }
  acc += __shfl_xor(acc, 8);
  acc += __shfl_xor(acc, 16);
  acc += __shfl_xor(acc, 32);
  if (eslot == 0) rden[r * 8 + hh] = 1.0f / (acc + 1e-16f);
}

// ---------------------------------------------------------------------------
// Propagate 1 (nodes -> hyperedges), gather form: wave per hyperedge c,
// lane = channel.  acc_e[c] = sum_r alpha * xh[r].  (Binv applied in prop2.)
__global__ __launch_bounds__(256) void prop1_csr(const int* __restrict__ cptr,
                                                 const int* __restrict__ csr_col_r,
                                                 const float* __restrict__ xh,
                                                 const float* __restrict__ s_i,
                                                 const float* __restrict__ s_j,
                                                 const float* __restrict__ rden,
                                                 float* __restrict__ acc_e) {
  int wid = (blockIdx.x * 256 + threadIdx.x) >> 6;
  int lane = threadIdx.x & 63;
  if (wid >= NN) return;
  int c = wid;
  int hh = lane >> 3;
  float sj = s_j[c * 8 + hh];
  int beg = cptr[c], end = cptr[c + 1];
  float acc = 0.f;
  for (int i = beg; i < end; ++i) {
    int r = csr_col_r[i];
    float a = s_i[r * 8 + hh] + sj;
    a = a > 0.f ? a : 0.2f * a;
    float alpha = expf(a) * rden[r * 8 + hh];
    acc += xh[(size_t)r * HID + lane] * alpha;
  }
  acc_e[(size_t)c * HID + lane] = acc;
}

// ---------------------------------------------------------------------------
// Propagate 2 (hyperedges -> nodes) + finish1 fused: wave per node r.
// h[r] = elu(Dinv * sum_c alpha*Binv[c]*acc_e[c] + b1).  D computed in-loop.
__global__ __launch_bounds__(256) void prop2_csr(const int* __restrict__ rptr,
                                                 const int* __restrict__ csr_row_c,
                                                 const float* __restrict__ acc_e,
                                                 const float* __restrict__ s_i,
                                                 const float* __restrict__ s_j,
                                                 const float* __restrict__ rden,
                                                 const float* __restrict__ Binv,
                                                 const float* __restrict__ hw,
                                                 const float* __restrict__ b1,
                                                 float* __restrict__ h) {
  int wid = (blockIdx.x * 256 + threadIdx.x) >> 6;
  int lane = threadIdx.x & 63;
  if (wid >= NN) return;
  int r = wid;
  int hh = lane >> 3;
  float si = s_i[r * 8 + hh];
  float rd = rden[r * 8 + hh];
  int beg = rptr[r], end = rptr[r + 1];
  float acc = 0.f, dsum = 0.f;
  for (int i = beg; i < end; ++i) {
    int c = csr_row_c[i];
    float a = si + s_j[c * 8 + hh];
    a = a > 0.f ? a : 0.2f * a;
    float alpha = expf(a) * rd;
    acc += acc_e[(size_t)c * HID + lane] * (Binv[c] * alpha);
    dsum += hw[c];
  }
  float dinv = dsum > 0.f ? 1.0f / dsum : 0.f;
  float v = fmaf(acc, dinv, b1[lane]);
  h[(size_t)r * HID + lane] = v > 0.f ? v : expm1f(v);
}

// ---------------------------------------------------------------------------
// GEMM2: xh2[n,k] = sum_c h[n,c]*W2[c,k]  (k<7; slot 7 zeroed)
__global__ __launch_bounds__(256) void gemm2_kernel(const float* __restrict__ h,
                                                    const float* __restrict__ W2,
                                                    float* __restrict__ xh2) {
  int t = blockIdx.x * 256 + threadIdx.x;
  if (t >= NN * 8) return;
  int n = t >> 3, k = t & 7;
  if (k == 7) { xh2[t] = 0.f; return; }
  const float* hp = h + (size_t)n * HID;
  float acc = 0.f;
#pragma unroll
  for (int c = 0; c < HID; ++c) acc = fmaf(hp[c], W2[c * NCLS + k], acc);
  xh2[t] = acc;
}

// ---------------------------------------------------------------------------
// Layer-2 propagate 1, gather form: 8 lanes per hyperedge.
__global__ __launch_bounds__(256) void prop3_csr(const int* __restrict__ cptr,
                                                 const int* __restrict__ csr_col_r,
                                                 const float* __restrict__ xh2,
                                                 float* __restrict__ acc_e2) {
  int t = blockIdx.x * 256 + threadIdx.x;
  int g = t >> 3, k = t & 7;
  if (g >= NN) return;
  int beg = cptr[g], end = cptr[g + 1];
  float acc = 0.f;
  for (int i = beg; i < end; ++i) {
    int r = csr_col_r[i];
    acc += xh2[(size_t)r * 8 + k];
  }
  acc_e2[(size_t)g * 8 + k] = acc;
}

// ---------------------------------------------------------------------------
// Layer-2 propagate 2 + log_softmax fused: 8 lanes per node.
__global__ __launch_bounds__(256) void prop4_csr(const int* __restrict__ rptr,
                                                 const int* __restrict__ csr_row_c,
                                                 const float* __restrict__ acc_e2,
                                                 const float* __restrict__ Binv,
                                                 const float* __restrict__ hw,
                                                 const float* __restrict__ b2,
                                                 float* __restrict__ out) {
  int t = blockIdx.x * 256 + threadIdx.x;
  int r = t >> 3, k = t & 7;
  if (r >= NN) return;
  int beg = rptr[r], end = rptr[r + 1];
  float acc = 0.f, dsum = 0.f;
  for (int i = beg; i < end; ++i) {
    int c = csr_row_c[i];
    acc += acc_e2[(size_t)c * 8 + k] * Binv[c];
    dsum += hw[c];
  }
  float dinv = dsum > 0.f ? 1.0f / dsum : 0.f;
  float v = (k < NCLS) ? fmaf(acc, dinv, b2[k]) : -INFINITY;
  float m = v;
  m = fmaxf(m, __shfl_xor(m, 1, 8));
  m = fmaxf(m, __shfl_xor(m, 2, 8));
  m = fmaxf(m, __shfl_xor(m, 4, 8));
  float ex = (k < NCLS) ? expf(v - m) : 0.f;
  float s = ex;
  s += __shfl_xor(s, 1, 8);
  s += __shfl_xor(s, 2, 8);
  s += __shfl_xor(s, 4, 8);
  float lse = m + logf(s);
  if (k < NCLS) out[(size_t)r * NCLS + k] = v - lse;
}

// ---------------------------------------------------------------------------
extern "C" void kernel_launch(void* const* d_in, const int* in_sizes, int n_in,
                              void* d_out, int out_size, void* d_ws, size_t ws_size,
                              hipStream_t stream) {
  const float* x    = (const float*)d_in[0];
  const int*   ei   = (const int*)d_in[1];
  const float* hw   = (const float*)d_in[2];
  const float* W1   = (const float*)d_in[3];
  const float* att1 = (const float*)d_in[4];
  const float* b1   = (const float*)d_in[5];
  const float* W2   = (const float*)d_in[6];
  const float* b2   = (const float*)d_in[7];
  float* out = (float*)d_out;
  float* ws  = (float*)d_ws;

  float* xh     = ws + OFF_XH;
  float* s_i    = ws + OFF_SI;
  float* s_j    = ws + OFF_SJ;
  float* rden   = ws + OFF_RDEN;
  float* Binv   = ws + OFF_BINV;
  float* acc_e  = ws + OFF_ACCE;
  float* hbuf   = ws + OFF_H;
  float* xh2    = ws + OFF_XH2;
  float* acc_e2 = ws + OFF_ACCE2;
  int* rptr = (int*)(ws + OFF_RPTR);
  int* cptr = (int*)(ws + OFF_CPTR);
  int* bh_r = (int*)(ws + OFF_BHR);
  int* bh_c = (int*)(ws + OFF_BHC);
  int* bs_r = (int*)(ws + OFF_BSR);
  int* bs_c = (int*)(ws + OFF_BSC);
  int* bc_r = (int*)(ws + OFF_BCR);
  int* bc_c = (int*)(ws + OFF_BCC);
  int* csr_row_c = (int*)(ws + OFF_CSRRC);
  int* csr_col_r = (int*)(ws + OFF_CSRCR);
  // temp packed-edge arrays alias xh / acc_e (consumed before those are written)
  int* tmp_r = (int*)(ws + OFF_XH);
  int* tmp_c = (int*)(ws + OFF_ACCE);

  // --- CSR build (bucketed counting sort, both orderings) ---
  zero_small<<<1, 512, 0, stream>>>(bh_r, bh_c);
  bucket_hist<<<256, 256, 0, stream>>>(ei, bh_r, bh_c);
  bucket_scan<<<1, 512, 0, stream>>>(bh_r, bh_c, bs_r, bs_c, bc_r, bc_c);
  phaseA<<<(EE + EPB - 1) / EPB, 256, 0, stream>>>(ei, bc_r, bc_c, tmp_r, tmp_c);
  phaseB<<<2 * NB, 256, 0, stream>>>(tmp_r, tmp_c, bs_r, bs_c, hw,
                                     rptr, cptr, csr_row_c, csr_col_r, Binv);

  // --- Layer 1 ---
  gemm1_kernel<<<(NN + 63) / 64, 256, 0, stream>>>(x, W1, xh);
  attscore_kernel<<<(NN * NHEAD + 255) / 256, 256, 0, stream>>>(xh, att1, s_i, s_j);
  den_csr<<<(NN * 64 + 255) / 256, 256, 0, stream>>>(rptr, csr_row_c, s_i, s_j, rden);
  prop1_csr<<<(NN * 64 + 255) / 256, 256, 0, stream>>>(cptr, csr_col_r, xh, s_i, s_j, rden, acc_e);
  prop2_csr<<<(NN * 64 + 255) / 256, 256, 0, stream>>>(rptr, csr_row_c, acc_e, s_i, s_j, rden,
                                                       Binv, hw, b1, hbuf);

  // --- Layer 2 ---
  gemm2_kernel<<<(NN * 8 + 255) / 256, 256, 0, stream>>>(hbuf, W2, xh2);
  prop3_csr<<<(NN * 8 + 255) / 256, 256, 0, stream>>>(cptr, csr_col_r, xh2, acc_e2);
  prop4_csr<<<(NN * 8 + 255) / 256, 256, 0, stream>>>(rptr, csr_row_c, acc_e2, Binv, hw, b2, out);
}

// Round 5
// 374.449 us; speedup vs baseline: 10.8407x; 1.5328x over previous
//
#include <hip/hip_runtime.h>
#include <hip/hip_bf16.h>
#include <cmath>

// Problem constants (match reference setup_inputs)
#define NN    50000
#define EE    1600000
#define FIN   512
#define NHEAD 8
#define OUT1  8
#define HID   64      // NHEAD*OUT1
#define NCLS  7

#define NB    391     // ceil(NN/128) buckets of 128 nodes
#define EPB   4096    // edges per block in phase A

// ---------------------------------------------------------------------------
// Workspace layout (4-byte elements):
//   xh      @ 0          N*64   (tmp_r aliases during CSR build)
//   s_j     @ 3,200,000  N*8
//   sird    @ 3,600,000  N*8 float2  {s_i, 1/den}  (800K floats)
//   dinv    @ 4,400,000  N
//   Binv    @ 4,450,000  N
//   acc_e   @ 4,500,000  N*64   (tmp_c aliases during CSR build)
//   h       @ 7,700,000  N*64
//   xh2     @ 10,900,000 N*8
//   acc_e2  @ 11,300,000 N*8
//   rptr    @ 11,700,000 N+1  int
//   cptr    @ 11,760,000 N+1  int
//   bh_r/bh_c/bs_r/bs_c/bc_r/bc_c @ 11,820,000 + k*1000
//   csr_row_c @ 11,830,000 E  int
//   csr_col_r @ 13,430,000 E  int
//   total 15,030,000 elems = 60.1 MB
// ---------------------------------------------------------------------------
#define OFF_XH     0
#define OFF_SJ     3200000
#define OFF_SIRD   3600000
#define OFF_DINV   4400000
#define OFF_BINV   4450000
#define OFF_ACCE   4500000
#define OFF_H      7700000
#define OFF_XH2    10900000
#define OFF_ACCE2  11300000
#define OFF_RPTR   11700000
#define OFF_CPTR   11760000
#define OFF_BHR    11820000
#define OFF_BHC    11821000
#define OFF_BSR    11822000
#define OFF_BSC    11823000
#define OFF_BCR    11824000
#define OFF_BCC    11825000
#define OFF_CSRRC  11830000
#define OFF_CSRCR  13430000

#define LRELU(a) ((a) > 0.f ? (a) : 0.2f * (a))

// ---------------------------------------------------------------------------
__global__ __launch_bounds__(512) void zero_small(int* __restrict__ bh_r,
                                                  int* __restrict__ bh_c) {
  int t = threadIdx.x;
  if (t <= NB) { bh_r[t] = 0; bh_c[t] = 0; }
}

// ---------------------------------------------------------------------------
__global__ __launch_bounds__(256) void bucket_hist(const int* __restrict__ ei,
                                                   int* __restrict__ bh_r,
                                                   int* __restrict__ bh_c) {
  __shared__ int hr[NB], hc[NB];
  int t = threadIdx.x;
  for (int i = t; i < NB; i += 256) { hr[i] = 0; hc[i] = 0; }
  __syncthreads();
  for (int i = blockIdx.x * 256 + t; i < EE; i += gridDim.x * 256) {
    atomicAdd(hr + (ei[i] >> 7), 1);
    atomicAdd(hc + (ei[EE + i] >> 7), 1);
  }
  __syncthreads();
  for (int i = t; i < NB; i += 256) {
    if (hr[i]) atomicAdd(bh_r + i, hr[i]);
    if (hc[i]) atomicAdd(bh_c + i, hc[i]);
  }
}

// ---------------------------------------------------------------------------
__global__ __launch_bounds__(512) void bucket_scan(const int* __restrict__ bh_r,
                                                   const int* __restrict__ bh_c,
                                                   int* __restrict__ bs_r,
                                                   int* __restrict__ bs_c,
                                                   int* __restrict__ bc_r,
                                                   int* __restrict__ bc_c) {
  __shared__ int lds[512];
  int t = threadIdx.x;
  for (int side = 0; side < 2; ++side) {
    const int* bh = side ? bh_c : bh_r;
    int* bs = side ? bs_c : bs_r;
    int* bc = side ? bc_c : bc_r;
    int v = (t < NB) ? bh[t] : 0;
    lds[t] = v;
    __syncthreads();
    for (int off = 1; off < 512; off <<= 1) {
      int u = (t >= off) ? lds[t - off] : 0;
      __syncthreads();
      lds[t] += u;
      __syncthreads();
    }
    int excl = lds[t] - v;
    if (t <= NB) bs[t] = excl;
    if (t < NB) bc[t] = excl;
    __syncthreads();
  }
}

// ---------------------------------------------------------------------------
__global__ __launch_bounds__(256) void phaseA(const int* __restrict__ ei,
                                              int* __restrict__ bc_r,
                                              int* __restrict__ bc_c,
                                              int* __restrict__ tmp_r,
                                              int* __restrict__ tmp_c) {
  __shared__ int er[EPB];
  __shared__ int ec[EPB];
  __shared__ int hr[NB], hc[NB];
  const int e0 = blockIdx.x * EPB;
  const int cntE = min(EPB, EE - e0);
  const int t = threadIdx.x;
  for (int i = t; i < cntE; i += 256) { er[i] = ei[e0 + i]; ec[i] = ei[EE + e0 + i]; }
  for (int i = t; i < NB; i += 256) { hr[i] = 0; hc[i] = 0; }
  __syncthreads();
  for (int i = t; i < cntE; i += 256) {
    atomicAdd(hr + (er[i] >> 7), 1);
    atomicAdd(hc + (ec[i] >> 7), 1);
  }
  __syncthreads();
  for (int i = t; i < NB; i += 256) {
    int n = hr[i];
    hr[i] = n ? atomicAdd(bc_r + i, n) : 0;
    n = hc[i];
    hc[i] = n ? atomicAdd(bc_c + i, n) : 0;
  }
  __syncthreads();
  for (int i = t; i < cntE; i += 256) {
    int r = er[i], c = ec[i];
    int pr = atomicAdd(hr + (r >> 7), 1);
    tmp_r[pr] = ((r & 127) << 16) | c;
    int pc = atomicAdd(hc + (c >> 7), 1);
    tmp_c[pc] = ((c & 127) << 16) | r;
  }
}

// ---------------------------------------------------------------------------
__global__ __launch_bounds__(256) void phaseB(const int* __restrict__ tmp_r,
                                              const int* __restrict__ tmp_c,
                                              const int* __restrict__ bs_r,
                                              const int* __restrict__ bs_c,
                                              const float* __restrict__ hw,
                                              int* __restrict__ rptr,
                                              int* __restrict__ cptr,
                                              int* __restrict__ csr_row_c,
                                              int* __restrict__ csr_col_r,
                                              float* __restrict__ Binv) {
  const int side = blockIdx.x >= NB ? 1 : 0;
  const int b = blockIdx.x - side * NB;
  const int* tmp = side ? tmp_c : tmp_r;
  const int* bs = side ? bs_c : bs_r;
  int* ptr = side ? cptr : rptr;
  int* csr = side ? csr_col_r : csr_row_c;

  const int base = bs[b];
  const int M = bs[b + 1] - base;
  __shared__ int cnt[128], pre[128], cur[128];
  const int t = threadIdx.x;
  if (t < 128) cnt[t] = 0;
  __syncthreads();
  for (int i = t; i < M; i += 256) atomicAdd(cnt + (tmp[base + i] >> 16), 1);
  __syncthreads();
  if (t < 128) pre[t] = cnt[t];
  __syncthreads();
  for (int off = 1; off < 128; off <<= 1) {
    int u = (t >= off && t < 128) ? pre[t - off] : 0;
    __syncthreads();
    if (t < 128) pre[t] += u;
    __syncthreads();
  }
  const int node0 = b << 7;
  if (t < 128) {
    int excl = pre[t] - cnt[t];
    int g = node0 + t;
    if (g <= NN) ptr[g] = base + excl;
    cur[t] = base + excl;
    if (side && g < NN) Binv[g] = cnt[t] > 0 ? hw[g] / (float)cnt[t] : 0.f;
  }
  __syncthreads();
  for (int i = t; i < M; i += 256) {
    int e = tmp[base + i];
    int pos = atomicAdd(cur + (e >> 16), 1);
    csr[pos] = e & 0xFFFF;
  }
}

// ---------------------------------------------------------------------------
// GEMM1: xh[N,64] = x[N,512] @ W1[512,64].
__global__ __launch_bounds__(256) void gemm1_kernel(const float* __restrict__ x,
                                                    const float* __restrict__ W1,
                                                    float* __restrict__ xh) {
  __shared__ float lx[32][68];
  __shared__ float lw[32][68];
  const int t = threadIdx.x;
  const int row0 = blockIdx.x * 64;
  const int ty = t >> 4, tx = t & 15;
  const int r0 = ty * 4, c0 = tx * 4;
  float acc[4][4] = {};

  for (int kb = 0; kb < FIN; kb += 32) {
    {
      int lr = t >> 2;
      int lk = (t & 3) * 8;
      int grow = row0 + lr;
      float4 a0, a1;
      if (grow < NN) {
        const float4* p = reinterpret_cast<const float4*>(x + (size_t)grow * FIN + kb + lk);
        a0 = p[0]; a1 = p[1];
      } else {
        a0 = make_float4(0.f, 0.f, 0.f, 0.f); a1 = a0;
      }
      lx[lk + 0][lr] = a0.x; lx[lk + 1][lr] = a0.y;
      lx[lk + 2][lr] = a0.z; lx[lk + 3][lr] = a0.w;
      lx[lk + 4][lr] = a1.x; lx[lk + 5][lr] = a1.y;
      lx[lk + 6][lr] = a1.z; lx[lk + 7][lr] = a1.w;
    }
    {
      int wk = t >> 3;
      int wc = (t & 7) * 8;
      const float4* q = reinterpret_cast<const float4*>(W1 + (size_t)(kb + wk) * HID + wc);
      float4 b0 = q[0], b1v = q[1];
      *reinterpret_cast<float4*>(&lw[wk][wc]) = b0;
      *reinterpret_cast<float4*>(&lw[wk][wc + 4]) = b1v;
    }
    __syncthreads();
#pragma unroll
    for (int kk = 0; kk < 32; ++kk) {
      const float4 af = *reinterpret_cast<const float4*>(&lx[kk][r0]);
      const float4 bf = *reinterpret_cast<const float4*>(&lw[kk][c0]);
      const float a4[4] = {af.x, af.y, af.z, af.w};
      const float b4[4] = {bf.x, bf.y, bf.z, bf.w};
#pragma unroll
      for (int i = 0; i < 4; ++i)
#pragma unroll
        for (int j = 0; j < 4; ++j)
          acc[i][j] = fmaf(a4[i], b4[j], acc[i][j]);
    }
    __syncthreads();
  }
#pragma unroll
  for (int i = 0; i < 4; ++i) {
    int gr = row0 + r0 + i;
    if (gr < NN) {
      float4 v = make_float4(acc[i][0], acc[i][1], acc[i][2], acc[i][3]);
      *reinterpret_cast<float4*>(xh + (size_t)gr * HID + c0) = v;
    }
  }
}

// ---------------------------------------------------------------------------
// Attention projections: sird[n*8+h].x = s_i, s_j[n*8+h] = s_j
__global__ __launch_bounds__(256) void attscore_kernel(const float* __restrict__ xh,
                                                       const float* __restrict__ att1,
                                                       float2* __restrict__ sird,
                                                       float* __restrict__ s_j) {
  int t = blockIdx.x * 256 + threadIdx.x;
  if (t >= NN * NHEAD) return;
  int n = t >> 3, hh = t & 7;
  const float* xp = xh + (size_t)n * HID + hh * OUT1;
  float si = 0.f, sj = 0.f;
#pragma unroll
  for (int c = 0; c < OUT1; ++c) {
    float v = xp[c];
    si = fmaf(v, att1[hh * 16 + c], si);
    sj = fmaf(v, att1[hh * 16 + 8 + c], sj);
  }
  sird[t] = make_float2(si, 0.f);
  s_j[t] = sj;
}

// ---------------------------------------------------------------------------
// Softmax denominator (reciprocal -> sird.y) + node degree (Dinv) per row.
// Wave per node; lanes = [8 eslots][8 heads].
__global__ __launch_bounds__(256) void den_csr(const int* __restrict__ rptr,
                                               const int* __restrict__ csr_row_c,
                                               const float* __restrict__ s_j,
                                               const float* __restrict__ hw,
                                               float2* __restrict__ sird,
                                               float* __restrict__ dinv) {
  int wid = (blockIdx.x * 256 + threadIdx.x) >> 6;
  int lane = threadIdx.x & 63;
  if (wid >= NN) return;
  int r = wid;
  int hh = lane & 7;
  int eslot = lane >> 3;
  float si = sird[r * 8 + hh].x;
  int beg = rptr[r], end = rptr[r + 1];
  float aexp = 0.f, ad = 0.f;
  int i = beg + eslot;
  for (; i + 8 < end; i += 16) {
    int c0 = csr_row_c[i], c1 = csr_row_c[i + 8];
    float sj0 = s_j[c0 * 8 + hh], sj1 = s_j[c1 * 8 + hh];
    float h0 = hw[c0], h1 = hw[c1];
    float a0 = LRELU(si + sj0), a1 = LRELU(si + sj1);
    aexp += expf(a0) + expf(a1);
    ad += h0 + h1;
  }
  if (i < end) {
    int c = csr_row_c[i];
    float a = LRELU(si + s_j[c * 8 + hh]);
    aexp += expf(a);
    ad += hw[c];
  }
  aexp += __shfl_xor(aexp, 8);
  aexp += __shfl_xor(aexp, 16);
  aexp += __shfl_xor(aexp, 32);
  ad += __shfl_xor(ad, 8);
  ad += __shfl_xor(ad, 16);
  ad += __shfl_xor(ad, 32);
  if (eslot == 0) {
    reinterpret_cast<float*>(sird)[(r * 8 + hh) * 2 + 1] = 1.0f / (aexp + 1e-16f);
    if (hh == 0) dinv[r] = ad > 0.f ? 1.0f / ad : 0.f;
  }
}

// ---------------------------------------------------------------------------
// Propagate 1 (nodes -> hyperedges): wave per hyperedge c, lane = channel.
// acc_e[c] = Binv[c] * sum_r alpha(r,c) * xh[r]   (Binv folded in here)
__global__ __launch_bounds__(256) void prop1_csr(const int* __restrict__ cptr,
                                                 const int* __restrict__ csr_col_r,
                                                 const float* __restrict__ xh,
                                                 const float2* __restrict__ sird,
                                                 const float* __restrict__ s_j,
                                                 const float* __restrict__ Binv,
                                                 float* __restrict__ acc_e) {
  int wid = (blockIdx.x * 256 + threadIdx.x) >> 6;
  int lane = threadIdx.x & 63;
  if (wid >= NN) return;
  int c = wid;
  int hh = lane >> 3;
  float sj = s_j[c * 8 + hh];
  int beg = cptr[c], end = cptr[c + 1];
  float acc = 0.f;
  int i = beg;
  for (; i + 3 < end; i += 4) {
    int r0 = csr_col_r[i], r1 = csr_col_r[i + 1];
    int r2 = csr_col_r[i + 2], r3 = csr_col_r[i + 3];
    float2 q0 = sird[r0 * 8 + hh];
    float2 q1 = sird[r1 * 8 + hh];
    float2 q2 = sird[r2 * 8 + hh];
    float2 q3 = sird[r3 * 8 + hh];
    float v0 = xh[(r0 << 6) + lane];
    float v1 = xh[(r1 << 6) + lane];
    float v2 = xh[(r2 << 6) + lane];
    float v3 = xh[(r3 << 6) + lane];
    float a0 = LRELU(q0.x + sj), a1 = LRELU(q1.x + sj);
    float a2 = LRELU(q2.x + sj), a3 = LRELU(q3.x + sj);
    acc = fmaf(v0, expf(a0) * q0.y, acc);
    acc = fmaf(v1, expf(a1) * q1.y, acc);
    acc = fmaf(v2, expf(a2) * q2.y, acc);
    acc = fmaf(v3, expf(a3) * q3.y, acc);
  }
  for (; i < end; ++i) {
    int r = csr_col_r[i];
    float2 q = sird[r * 8 + hh];
    float v = xh[(r << 6) + lane];
    float a = LRELU(q.x + sj);
    acc = fmaf(v, expf(a) * q.y, acc);
  }
  acc_e[(c << 6) + lane] = acc * Binv[c];
}

// ---------------------------------------------------------------------------
// Propagate 2 (hyperedges -> nodes) + finish1: wave per node r.
// h[r] = elu(Dinv[r] * sum_c alpha(r,c) * acc_e[c] + b1)  (acc_e pre-scaled)
__global__ __launch_bounds__(256) void prop2_csr(const int* __restrict__ rptr,
                                                 const int* __restrict__ csr_row_c,
                                                 const float* __restrict__ acc_e,
                                                 const float2* __restrict__ sird,
                                                 const float* __restrict__ s_j,
                                                 const float* __restrict__ dinv,
                                                 const float* __restrict__ b1,
                                                 float* __restrict__ h) {
  int wid = (blockIdx.x * 256 + threadIdx.x) >> 6;
  int lane = threadIdx.x & 63;
  if (wid >= NN) return;
  int r = wid;
  int hh = lane >> 3;
  float2 sr = sird[r * 8 + hh];
  float si = sr.x, rd = sr.y;
  int beg = rptr[r], end = rptr[r + 1];
  float acc = 0.f;
  int i = beg;
  for (; i + 3 < end; i += 4) {
    int c0 = csr_row_c[i], c1 = csr_row_c[i + 1];
    int c2 = csr_row_c[i + 2], c3 = csr_row_c[i + 3];
    float sj0 = s_j[c0 * 8 + hh], sj1 = s_j[c1 * 8 + hh];
    float sj2 = s_j[c2 * 8 + hh], sj3 = s_j[c3 * 8 + hh];
    float v0 = acc_e[(c0 << 6) + lane];
    float v1 = acc_e[(c1 << 6) + lane];
    float v2 = acc_e[(c2 << 6) + lane];
    float v3 = acc_e[(c3 << 6) + lane];
    float a0 = LRELU(si + sj0), a1 = LRELU(si + sj1);
    float a2 = LRELU(si + sj2), a3 = LRELU(si + sj3);
    acc = fmaf(v0, expf(a0), acc * 1.0f);
    acc = fmaf(v1, expf(a1), acc);
    acc = fmaf(v2, expf(a2), acc);
    acc = fmaf(v3, expf(a3), acc);
  }
  for (; i < end; ++i) {
    int c = csr_row_c[i];
    float sj = s_j[c * 8 + hh];
    float v = acc_e[(c << 6) + lane];
    float a = LRELU(si + sj);
    acc = fmaf(v, expf(a), acc);
  }
  acc *= rd;  // common softmax reciprocal factored out of the loop
  float v = fmaf(acc, dinv[r], b1[lane]);
  h[(r << 6) + lane] = v > 0.f ? v : expm1f(v);
}

// ---------------------------------------------------------------------------
// GEMM2: xh2[n,k] = sum_c h[n,c]*W2[c,k]  (k<7; slot 7 zeroed)
__global__ __launch_bounds__(256) void gemm2_kernel(const float* __restrict__ h,
                                                    const float* __restrict__ W2,
                                                    float* __restrict__ xh2) {
  int t = blockIdx.x * 256 + threadIdx.x;
  if (t >= NN * 8) return;
  int n = t >> 3, k = t & 7;
  if (k == 7) { xh2[t] = 0.f; return; }
  const float* hp = h + (size_t)n * HID;
  float acc = 0.f;
#pragma unroll
  for (int c = 0; c < HID; ++c) acc = fmaf(hp[c], W2[c * NCLS + k], acc);
  xh2[t] = acc;
}

// ---------------------------------------------------------------------------
// Layer-2 propagate 1: acc_e2[g] = Binv[g] * sum_r xh2[r]   (Binv folded in)
__global__ __launch_bounds__(256) void prop3_csr(const int* __restrict__ cptr,
                                                 const int* __restrict__ csr_col_r,
                                                 const float* __restrict__ xh2,
                                                 const float* __restrict__ Binv,
                                                 float* __restrict__ acc_e2) {
  int t = blockIdx.x * 256 + threadIdx.x;
  int g = t >> 3, k = t & 7;
  if (g >= NN) return;
  int beg = cptr[g], end = cptr[g + 1];
  float acc = 0.f;
  int i = beg;
  for (; i + 3 < end; i += 4) {
    int r0 = csr_col_r[i], r1 = csr_col_r[i + 1];
    int r2 = csr_col_r[i + 2], r3 = csr_col_r[i + 3];
    float v0 = xh2[r0 * 8 + k], v1 = xh2[r1 * 8 + k];
    float v2 = xh2[r2 * 8 + k], v3 = xh2[r3 * 8 + k];
    acc += (v0 + v1) + (v2 + v3);
  }
  for (; i < end; ++i) acc += xh2[csr_col_r[i] * 8 + k];
  acc_e2[g * 8 + k] = acc * Binv[g];
}

// ---------------------------------------------------------------------------
// Layer-2 propagate 2 + log_softmax: 8 lanes per node.
__global__ __launch_bounds__(256) void prop4_csr(const int* __restrict__ rptr,
                                                 const int* __restrict__ csr_row_c,
                                                 const float* __restrict__ acc_e2,
                                                 const float* __restrict__ dinv,
                                                 const float* __restrict__ b2,
                                                 float* __restrict__ out) {
  int t = blockIdx.x * 256 + threadIdx.x;
  int r = t >> 3, k = t & 7;
  if (r >= NN) return;
  int beg = rptr[r], end = rptr[r + 1];
  float acc = 0.f;
  int i = beg;
  for (; i + 3 < end; i += 4) {
    int c0 = csr_row_c[i], c1 = csr_row_c[i + 1];
    int c2 = csr_row_c[i + 2], c3 = csr_row_c[i + 3];
    float v0 = acc_e2[c0 * 8 + k], v1 = acc_e2[c1 * 8 + k];
    float v2 = acc_e2[c2 * 8 + k], v3 = acc_e2[c3 * 8 + k];
    acc += (v0 + v1) + (v2 + v3);
  }
  for (; i < end; ++i) acc += acc_e2[csr_row_c[i] * 8 + k];
  float v = (k < NCLS) ? fmaf(acc, dinv[r], b2[k]) : -INFINITY;
  float m = v;
  m = fmaxf(m, __shfl_xor(m, 1, 8));
  m = fmaxf(m, __shfl_xor(m, 2, 8));
  m = fmaxf(m, __shfl_xor(m, 4, 8));
  float ex = (k < NCLS) ? expf(v - m) : 0.f;
  float s = ex;
  s += __shfl_xor(s, 1, 8);
  s += __shfl_xor(s, 2, 8);
  s += __shfl_xor(s, 4, 8);
  float lse = m + logf(s);
  if (k < NCLS) out[(size_t)r * NCLS + k] = v - lse;
}

// ---------------------------------------------------------------------------
extern "C" void kernel_launch(void* const* d_in, const int* in_sizes, int n_in,
                              void* d_out, int out_size, void* d_ws, size_t ws_size,
                              hipStream_t stream) {
  const float* x    = (const float*)d_in[0];
  const int*   ei   = (const int*)d_in[1];
  const float* hw   = (const float*)d_in[2];
  const float* W1   = (const float*)d_in[3];
  const float* att1 = (const float*)d_in[4];
  const float* b1   = (const float*)d_in[5];
  const float* W2   = (const float*)d_in[6];
  const float* b2   = (const float*)d_in[7];
  float* out = (float*)d_out;
  float* ws  = (float*)d_ws;

  float* xh     = ws + OFF_XH;
  float* s_j    = ws + OFF_SJ;
  float2* sird  = (float2*)(ws + OFF_SIRD);
  float* dinv   = ws + OFF_DINV;
  float* Binv   = ws + OFF_BINV;
  float* acc_e  = ws + OFF_ACCE;
  float* hbuf   = ws + OFF_H;
  float* xh2    = ws + OFF_XH2;
  float* acc_e2 = ws + OFF_ACCE2;
  int* rptr = (int*)(ws + OFF_RPTR);
  int* cptr = (int*)(ws + OFF_CPTR);
  int* bh_r = (int*)(ws + OFF_BHR);
  int* bh_c = (int*)(ws + OFF_BHC);
  int* bs_r = (int*)(ws + OFF_BSR);
  int* bs_c = (int*)(ws + OFF_BSC);
  int* bc_r = (int*)(ws + OFF_BCR);
  int* bc_c = (int*)(ws + OFF_BCC);
  int* csr_row_c = (int*)(ws + OFF_CSRRC);
  int* csr_col_r = (int*)(ws + OFF_CSRCR);
  int* tmp_r = (int*)(ws + OFF_XH);    // aliases xh (consumed before xh written)
  int* tmp_c = (int*)(ws + OFF_ACCE);  // aliases acc_e

  // --- CSR build (bucketed counting sort, both orderings) ---
  zero_small<<<1, 512, 0, stream>>>(bh_r, bh_c);
  bucket_hist<<<256, 256, 0, stream>>>(ei, bh_r, bh_c);
  bucket_scan<<<1, 512, 0, stream>>>(bh_r, bh_c, bs_r, bs_c, bc_r, bc_c);
  phaseA<<<(EE + EPB - 1) / EPB, 256, 0, stream>>>(ei, bc_r, bc_c, tmp_r, tmp_c);
  phaseB<<<2 * NB, 256, 0, stream>>>(tmp_r, tmp_c, bs_r, bs_c, hw,
                                     rptr, cptr, csr_row_c, csr_col_r, Binv);

  // --- Layer 1 ---
  gemm1_kernel<<<(NN + 63) / 64, 256, 0, stream>>>(x, W1, xh);
  attscore_kernel<<<(NN * NHEAD + 255) / 256, 256, 0, stream>>>(xh, att1, sird, s_j);
  den_csr<<<(NN * 64 + 255) / 256, 256, 0, stream>>>(rptr, csr_row_c, s_j, hw, sird, dinv);
  prop1_csr<<<(NN * 64 + 255) / 256, 256, 0, stream>>>(cptr, csr_col_r, xh, sird, s_j, Binv, acc_e);
  prop2_csr<<<(NN * 64 + 255) / 256, 256, 0, stream>>>(rptr, csr_row_c, acc_e, sird, s_j,
                                                       dinv, b1, hbuf);

  // --- Layer 2 ---
  gemm2_kernel<<<(NN * 8 + 255) / 256, 256, 0, stream>>>(hbuf, W2, xh2);
  prop3_csr<<<(NN * 8 + 255) / 256, 256, 0, stream>>>(cptr, csr_col_r, xh2, Binv, acc_e2);
  prop4_csr<<<(NN * 8 + 255) / 256, 256, 0, stream>>>(rptr, csr_row_c, acc_e2, dinv, b2, out);
}

// Round 6
// 353.950 us; speedup vs baseline: 11.4685x; 1.0579x over previous
//
#include <hip/hip_runtime.h>
#include <hip/hip_bf16.h>
#include <cmath>

// Problem constants (match reference setup_inputs)
#define NN    50000
#define EE    1600000
#define FIN   512
#define NHEAD 8
#define OUT1  8
#define HID   64      // NHEAD*OUT1
#define NCLS  7

#define NB    391     // ceil(NN/128) buckets of 128 nodes
#define EPB   4096    // edges per block in phase A
#define LOG2E 1.4426950408889634f

// ---------------------------------------------------------------------------
// Workspace layout (4-byte elements):
//   xh      @ 0          N*64   (tmp_r aliases during CSR build)
//   s_j     @ 3,200,000  N*8    (pre-scaled by log2e)
//   sird    @ 3,600,000  N*8 float2  {s_i*log2e, 1/den}
//   dinv    @ 4,400,000  N
//   Binv    @ 4,450,000  N
//   acc_e   @ 4,500,000  N*64   (tmp_c aliases during CSR build)
//   h       @ 7,700,000  N*64
//   xh2     @ 10,900,000 N*8
//   acc_e2  @ 11,300,000 N*8
//   rptr    @ 11,700,000 N+1  int
//   cptr    @ 11,760,000 N+1  int
//   bh_r/bh_c/bs_r/bs_c/bc_r/bc_c @ 11,820,000 + k*1000
//   csr_row_c @ 11,830,000 E  int
//   csr_col_r @ 13,430,000 E  int
// ---------------------------------------------------------------------------
#define OFF_XH     0
#define OFF_SJ     3200000
#define OFF_SIRD   3600000
#define OFF_DINV   4400000
#define OFF_BINV   4450000
#define OFF_ACCE   4500000
#define OFF_H      7700000
#define OFF_XH2    10900000
#define OFF_ACCE2  11300000
#define OFF_RPTR   11700000
#define OFF_CPTR   11760000
#define OFF_BHR    11820000
#define OFF_BHC    11821000
#define OFF_BSR    11822000
#define OFF_BSC    11823000
#define OFF_BCR    11824000
#define OFF_BCC    11825000
#define OFF_CSRRC  11830000
#define OFF_CSRCR  13430000

#define LRELU(a) ((a) > 0.f ? (a) : 0.2f * (a))

__device__ __forceinline__ float fexp2(float x) {
#if __has_builtin(__builtin_amdgcn_exp2f)
  return __builtin_amdgcn_exp2f(x);
#else
  return exp2f(x);
#endif
}

// ---------------------------------------------------------------------------
__global__ __launch_bounds__(512) void zero_small(int* __restrict__ bh_r,
                                                  int* __restrict__ bh_c) {
  int t = threadIdx.x;
  if (t <= NB) { bh_r[t] = 0; bh_c[t] = 0; }
}

// ---------------------------------------------------------------------------
__global__ __launch_bounds__(256) void bucket_hist(const int* __restrict__ ei,
                                                   int* __restrict__ bh_r,
                                                   int* __restrict__ bh_c) {
  __shared__ int hr[NB], hc[NB];
  int t = threadIdx.x;
  for (int i = t; i < NB; i += 256) { hr[i] = 0; hc[i] = 0; }
  __syncthreads();
  for (int i = blockIdx.x * 256 + t; i < EE; i += gridDim.x * 256) {
    atomicAdd(hr + (ei[i] >> 7), 1);
    atomicAdd(hc + (ei[EE + i] >> 7), 1);
  }
  __syncthreads();
  for (int i = t; i < NB; i += 256) {
    if (hr[i]) atomicAdd(bh_r + i, hr[i]);
    if (hc[i]) atomicAdd(bh_c + i, hc[i]);
  }
}

// ---------------------------------------------------------------------------
__global__ __launch_bounds__(512) void bucket_scan(const int* __restrict__ bh_r,
                                                   const int* __restrict__ bh_c,
                                                   int* __restrict__ bs_r,
                                                   int* __restrict__ bs_c,
                                                   int* __restrict__ bc_r,
                                                   int* __restrict__ bc_c) {
  __shared__ int lds[512];
  int t = threadIdx.x;
  for (int side = 0; side < 2; ++side) {
    const int* bh = side ? bh_c : bh_r;
    int* bs = side ? bs_c : bs_r;
    int* bc = side ? bc_c : bc_r;
    int v = (t < NB) ? bh[t] : 0;
    lds[t] = v;
    __syncthreads();
    for (int off = 1; off < 512; off <<= 1) {
      int u = (t >= off) ? lds[t - off] : 0;
      __syncthreads();
      lds[t] += u;
      __syncthreads();
    }
    int excl = lds[t] - v;
    if (t <= NB) bs[t] = excl;
    if (t < NB) bc[t] = excl;
    __syncthreads();
  }
}

// ---------------------------------------------------------------------------
__global__ __launch_bounds__(256) void phaseA(const int* __restrict__ ei,
                                              int* __restrict__ bc_r,
                                              int* __restrict__ bc_c,
                                              int* __restrict__ tmp_r,
                                              int* __restrict__ tmp_c) {
  __shared__ int er[EPB];
  __shared__ int ec[EPB];
  __shared__ int hr[NB], hc[NB];
  const int e0 = blockIdx.x * EPB;
  const int cntE = min(EPB, EE - e0);
  const int t = threadIdx.x;
  for (int i = t; i < cntE; i += 256) { er[i] = ei[e0 + i]; ec[i] = ei[EE + e0 + i]; }
  for (int i = t; i < NB; i += 256) { hr[i] = 0; hc[i] = 0; }
  __syncthreads();
  for (int i = t; i < cntE; i += 256) {
    atomicAdd(hr + (er[i] >> 7), 1);
    atomicAdd(hc + (ec[i] >> 7), 1);
  }
  __syncthreads();
  for (int i = t; i < NB; i += 256) {
    int n = hr[i];
    hr[i] = n ? atomicAdd(bc_r + i, n) : 0;
    n = hc[i];
    hc[i] = n ? atomicAdd(bc_c + i, n) : 0;
  }
  __syncthreads();
  for (int i = t; i < cntE; i += 256) {
    int r = er[i], c = ec[i];
    int pr = atomicAdd(hr + (r >> 7), 1);
    tmp_r[pr] = ((r & 127) << 16) | c;
    int pc = atomicAdd(hc + (c >> 7), 1);
    tmp_c[pc] = ((c & 127) << 16) | r;
  }
}

// ---------------------------------------------------------------------------
__global__ __launch_bounds__(256) void phaseB(const int* __restrict__ tmp_r,
                                              const int* __restrict__ tmp_c,
                                              const int* __restrict__ bs_r,
                                              const int* __restrict__ bs_c,
                                              const float* __restrict__ hw,
                                              int* __restrict__ rptr,
                                              int* __restrict__ cptr,
                                              int* __restrict__ csr_row_c,
                                              int* __restrict__ csr_col_r,
                                              float* __restrict__ Binv) {
  const int side = blockIdx.x >= NB ? 1 : 0;
  const int b = blockIdx.x - side * NB;
  const int* tmp = side ? tmp_c : tmp_r;
  const int* bs = side ? bs_c : bs_r;
  int* ptr = side ? cptr : rptr;
  int* csr = side ? csr_col_r : csr_row_c;

  const int base = bs[b];
  const int M = bs[b + 1] - base;
  __shared__ int cnt[128], pre[128], cur[128];
  const int t = threadIdx.x;
  if (t < 128) cnt[t] = 0;
  __syncthreads();
  for (int i = t; i < M; i += 256) atomicAdd(cnt + (tmp[base + i] >> 16), 1);
  __syncthreads();
  if (t < 128) pre[t] = cnt[t];
  __syncthreads();
  for (int off = 1; off < 128; off <<= 1) {
    int u = (t >= off && t < 128) ? pre[t - off] : 0;
    __syncthreads();
    if (t < 128) pre[t] += u;
    __syncthreads();
  }
  const int node0 = b << 7;
  if (t < 128) {
    int excl = pre[t] - cnt[t];
    int g = node0 + t;
    if (g <= NN) ptr[g] = base + excl;
    cur[t] = base + excl;
    if (side && g < NN) Binv[g] = cnt[t] > 0 ? hw[g] / (float)cnt[t] : 0.f;
  }
  __syncthreads();
  for (int i = t; i < M; i += 256) {
    int e = tmp[base + i];
    int pos = atomicAdd(cur + (e >> 16), 1);
    csr[pos] = e & 0xFFFF;
  }
}

// ---------------------------------------------------------------------------
// GEMM1: xh[N,64] = x[N,512] @ W1[512,64].
__global__ __launch_bounds__(256) void gemm1_kernel(const float* __restrict__ x,
                                                    const float* __restrict__ W1,
                                                    float* __restrict__ xh) {
  __shared__ float lx[32][68];
  __shared__ float lw[32][68];
  const int t = threadIdx.x;
  const int row0 = blockIdx.x * 64;
  const int ty = t >> 4, tx = t & 15;
  const int r0 = ty * 4, c0 = tx * 4;
  float acc[4][4] = {};

  for (int kb = 0; kb < FIN; kb += 32) {
    {
      int lr = t >> 2;
      int lk = (t & 3) * 8;
      int grow = row0 + lr;
      float4 a0, a1;
      if (grow < NN) {
        const float4* p = reinterpret_cast<const float4*>(x + (size_t)grow * FIN + kb + lk);
        a0 = p[0]; a1 = p[1];
      } else {
        a0 = make_float4(0.f, 0.f, 0.f, 0.f); a1 = a0;
      }
      lx[lk + 0][lr] = a0.x; lx[lk + 1][lr] = a0.y;
      lx[lk + 2][lr] = a0.z; lx[lk + 3][lr] = a0.w;
      lx[lk + 4][lr] = a1.x; lx[lk + 5][lr] = a1.y;
      lx[lk + 6][lr] = a1.z; lx[lk + 7][lr] = a1.w;
    }
    {
      int wk = t >> 3;
      int wc = (t & 7) * 8;
      const float4* q = reinterpret_cast<const float4*>(W1 + (size_t)(kb + wk) * HID + wc);
      float4 b0 = q[0], b1v = q[1];
      *reinterpret_cast<float4*>(&lw[wk][wc]) = b0;
      *reinterpret_cast<float4*>(&lw[wk][wc + 4]) = b1v;
    }
    __syncthreads();
#pragma unroll
    for (int kk = 0; kk < 32; ++kk) {
      const float4 af = *reinterpret_cast<const float4*>(&lx[kk][r0]);
      const float4 bf = *reinterpret_cast<const float4*>(&lw[kk][c0]);
      const float a4[4] = {af.x, af.y, af.z, af.w};
      const float b4[4] = {bf.x, bf.y, bf.z, bf.w};
#pragma unroll
      for (int i = 0; i < 4; ++i)
#pragma unroll
        for (int j = 0; j < 4; ++j)
          acc[i][j] = fmaf(a4[i], b4[j], acc[i][j]);
    }
    __syncthreads();
  }
#pragma unroll
  for (int i = 0; i < 4; ++i) {
    int gr = row0 + r0 + i;
    if (gr < NN) {
      float4 v = make_float4(acc[i][0], acc[i][1], acc[i][2], acc[i][3]);
      *reinterpret_cast<float4*>(xh + (size_t)gr * HID + c0) = v;
    }
  }
}

// ---------------------------------------------------------------------------
// Attention projections, PRE-SCALED by log2e so all exps become exp2.
__global__ __launch_bounds__(256) void attscore_kernel(const float* __restrict__ xh,
                                                       const float* __restrict__ att1,
                                                       float2* __restrict__ sird,
                                                       float* __restrict__ s_j) {
  int t = blockIdx.x * 256 + threadIdx.x;
  if (t >= NN * NHEAD) return;
  int n = t >> 3, hh = t & 7;
  const float* xp = xh + (size_t)n * HID + hh * OUT1;
  float si = 0.f, sj = 0.f;
#pragma unroll
  for (int c = 0; c < OUT1; ++c) {
    float v = xp[c];
    si = fmaf(v, att1[hh * 16 + c], si);
    sj = fmaf(v, att1[hh * 16 + 8 + c], sj);
  }
  sird[t] = make_float2(si * LOG2E, 0.f);
  s_j[t] = sj * LOG2E;
}

// ---------------------------------------------------------------------------
// Softmax denominator (reciprocal -> sird.y) + node degree (Dinv) per row.
__global__ __launch_bounds__(256) void den_csr(const int* __restrict__ rptr,
                                               const int* __restrict__ csr_row_c,
                                               const float* __restrict__ s_j,
                                               const float* __restrict__ hw,
                                               float2* __restrict__ sird,
                                               float* __restrict__ dinv) {
  int wid = (blockIdx.x * 256 + threadIdx.x) >> 6;
  int lane = threadIdx.x & 63;
  if (wid >= NN) return;
  int r = wid;
  int hh = lane & 7;
  int eslot = lane >> 3;
  float si = sird[r * 8 + hh].x;
  int beg = rptr[r], end = rptr[r + 1];
  float aexp = 0.f, ad = 0.f;
  int i = beg + eslot;
  for (; i + 8 < end; i += 16) {
    int c0 = csr_row_c[i], c1 = csr_row_c[i + 8];
    float sj0 = s_j[c0 * 8 + hh], sj1 = s_j[c1 * 8 + hh];
    float h0 = hw[c0], h1 = hw[c1];
    float a0 = LRELU(si + sj0), a1 = LRELU(si + sj1);
    aexp += fexp2(a0) + fexp2(a1);
    ad += h0 + h1;
  }
  if (i < end) {
    int c = csr_row_c[i];
    float a = LRELU(si + s_j[c * 8 + hh]);
    aexp += fexp2(a);
    ad += hw[c];
  }
  aexp += __shfl_xor(aexp, 8);
  aexp += __shfl_xor(aexp, 16);
  aexp += __shfl_xor(aexp, 32);
  ad += __shfl_xor(ad, 8);
  ad += __shfl_xor(ad, 16);
  ad += __shfl_xor(ad, 32);
  if (eslot == 0) {
    reinterpret_cast<float*>(sird)[(r * 8 + hh) * 2 + 1] = 1.0f / (aexp + 1e-16f);
    if (hh == 0) dinv[r] = ad > 0.f ? 1.0f / ad : 0.f;
  }
}

// ---------------------------------------------------------------------------
// Propagate 1 (nodes -> hyperedges): wave per hyperedge c, lane = channel.
// 8-edge batches: lane (hh*8+j) computes alpha(edge j, head hh) ONCE, then
// shuffles distribute r (uniform idx) and alpha (per-lane idx) for the fmas.
__global__ __launch_bounds__(256) void prop1_csr(const int* __restrict__ cptr,
                                                 const int* __restrict__ csr_col_r,
                                                 const float* __restrict__ xh,
                                                 const float2* __restrict__ sird,
                                                 const float* __restrict__ s_j,
                                                 const float* __restrict__ Binv,
                                                 float* __restrict__ acc_e) {
  int wid = (blockIdx.x * 256 + threadIdx.x) >> 6;
  int lane = threadIdx.x & 63;
  if (wid >= NN) return;
  const int c = wid;
  const int hh = lane >> 3;
  const int j = lane & 7;
  const int abase = lane & 56;  // hh*8: shfl source base for my head's alphas
  float sj = s_j[c * 8 + hh];
  int beg = cptr[c], end = cptr[c + 1];
  float acc = 0.f;
  int i = beg;
  for (; i + 8 <= end; i += 8) {
    int rj = csr_col_r[i + j];
    float2 q = sird[rj * 8 + hh];
    float a = LRELU(q.x + sj);
    float aexp = fexp2(a) * q.y;  // alpha(edge j, head hh)
#pragma unroll
    for (int j2 = 0; j2 < 8; ++j2) {
      int r = __shfl(rj, j2);
      float al = __shfl(aexp, abase + j2);
      acc = fmaf(xh[(r << 6) + lane], al, acc);
    }
  }
  for (; i < end; ++i) {
    int r = csr_col_r[i];
    float2 q = sird[r * 8 + hh];
    float a = LRELU(q.x + sj);
    acc = fmaf(xh[(r << 6) + lane], fexp2(a) * q.y, acc);
  }
  acc_e[(c << 6) + lane] = acc * Binv[c];
}

// ---------------------------------------------------------------------------
// Propagate 2 (hyperedges -> nodes) + finish1: wave per node r, same batching.
__global__ __launch_bounds__(256) void prop2_csr(const int* __restrict__ rptr,
                                                 const int* __restrict__ csr_row_c,
                                                 const float* __restrict__ acc_e,
                                                 const float2* __restrict__ sird,
                                                 const float* __restrict__ s_j,
                                                 const float* __restrict__ dinv,
                                                 const float* __restrict__ b1,
                                                 float* __restrict__ h) {
  int wid = (blockIdx.x * 256 + threadIdx.x) >> 6;
  int lane = threadIdx.x & 63;
  if (wid >= NN) return;
  const int r = wid;
  const int hh = lane >> 3;
  const int j = lane & 7;
  const int abase = lane & 56;
  float2 sr = sird[r * 8 + hh];
  const float si = sr.x, rd = sr.y;
  int beg = rptr[r], end = rptr[r + 1];
  float acc = 0.f;
  int i = beg;
  for (; i + 8 <= end; i += 8) {
    int cj = csr_row_c[i + j];
    float sjv = s_j[cj * 8 + hh];
    float aexp = fexp2(LRELU(si + sjv));  // exp(a) for (edge j, head hh)
#pragma unroll
    for (int j2 = 0; j2 < 8; ++j2) {
      int cc = __shfl(cj, j2);
      float al = __shfl(aexp, abase + j2);
      acc = fmaf(acc_e[(cc << 6) + lane], al, acc);
    }
  }
  for (; i < end; ++i) {
    int cc = csr_row_c[i];
    float aexp = fexp2(LRELU(si + s_j[cc * 8 + hh]));
    acc = fmaf(acc_e[(cc << 6) + lane], aexp, acc);
  }
  acc *= rd;  // softmax reciprocal factored out of the loop
  float v = fmaf(acc, dinv[r], b1[lane]);
  h[(r << 6) + lane] = v > 0.f ? v : expm1f(v);
}

// ---------------------------------------------------------------------------
// GEMM2: xh2[n,k] = sum_c h[n,c]*W2[c,k]  (k<7; slot 7 zeroed)
__global__ __launch_bounds__(256) void gemm2_kernel(const float* __restrict__ h,
                                                    const float* __restrict__ W2,
                                                    float* __restrict__ xh2) {
  int t = blockIdx.x * 256 + threadIdx.x;
  if (t >= NN * 8) return;
  int n = t >> 3, k = t & 7;
  if (k == 7) { xh2[t] = 0.f; return; }
  const float* hp = h + (size_t)n * HID;
  float acc = 0.f;
#pragma unroll
  for (int c = 0; c < HID; ++c) acc = fmaf(hp[c], W2[c * NCLS + k], acc);
  xh2[t] = acc;
}

// ---------------------------------------------------------------------------
// Layer-2 propagate 1: acc_e2[g] = Binv[g] * sum_r xh2[r]
__global__ __launch_bounds__(256) void prop3_csr(const int* __restrict__ cptr,
                                                 const int* __restrict__ csr_col_r,
                                                 const float* __restrict__ xh2,
                                                 const float* __restrict__ Binv,
                                                 float* __restrict__ acc_e2) {
  int t = blockIdx.x * 256 + threadIdx.x;
  int g = t >> 3, k = t & 7;
  if (g >= NN) return;
  int beg = cptr[g], end = cptr[g + 1];
  float acc = 0.f;
  int i = beg;
  for (; i + 3 < end; i += 4) {
    int r0 = csr_col_r[i], r1 = csr_col_r[i + 1];
    int r2 = csr_col_r[i + 2], r3 = csr_col_r[i + 3];
    float v0 = xh2[r0 * 8 + k], v1 = xh2[r1 * 8 + k];
    float v2 = xh2[r2 * 8 + k], v3 = xh2[r3 * 8 + k];
    acc += (v0 + v1) + (v2 + v3);
  }
  for (; i < end; ++i) acc += xh2[csr_col_r[i] * 8 + k];
  acc_e2[g * 8 + k] = acc * Binv[g];
}

// ---------------------------------------------------------------------------
// Layer-2 propagate 2 + log_softmax: 8 lanes per node.
__global__ __launch_bounds__(256) void prop4_csr(const int* __restrict__ rptr,
                                                 const int* __restrict__ csr_row_c,
                                                 const float* __restrict__ acc_e2,
                                                 const float* __restrict__ dinv,
                                                 const float* __restrict__ b2,
                                                 float* __restrict__ out) {
  int t = blockIdx.x * 256 + threadIdx.x;
  int r = t >> 3, k = t & 7;
  if (r >= NN) return;
  int beg = rptr[r], end = rptr[r + 1];
  float acc = 0.f;
  int i = beg;
  for (; i + 3 < end; i += 4) {
    int c0 = csr_row_c[i], c1 = csr_row_c[i + 1];
    int c2 = csr_row_c[i + 2], c3 = csr_row_c[i + 3];
    float v0 = acc_e2[c0 * 8 + k], v1 = acc_e2[c1 * 8 + k];
    float v2 = acc_e2[c2 * 8 + k], v3 = acc_e2[c3 * 8 + k];
    acc += (v0 + v1) + (v2 + v3);
  }
  for (; i < end; ++i) acc += acc_e2[csr_row_c[i] * 8 + k];
  float v = (k < NCLS) ? fmaf(acc, dinv[r], b2[k]) : -INFINITY;
  float m = v;
  m = fmaxf(m, __shfl_xor(m, 1, 8));
  m = fmaxf(m, __shfl_xor(m, 2, 8));
  m = fmaxf(m, __shfl_xor(m, 4, 8));
  float ex = (k < NCLS) ? expf(v - m) : 0.f;
  float s = ex;
  s += __shfl_xor(s, 1, 8);
  s += __shfl_xor(s, 2, 8);
  s += __shfl_xor(s, 4, 8);
  float lse = m + logf(s);
  if (k < NCLS) out[(size_t)r * NCLS + k] = v - lse;
}

// ---------------------------------------------------------------------------
extern "C" void kernel_launch(void* const* d_in, const int* in_sizes, int n_in,
                              void* d_out, int out_size, void* d_ws, size_t ws_size,
                              hipStream_t stream) {
  const float* x    = (const float*)d_in[0];
  const int*   ei   = (const int*)d_in[1];
  const float* hw   = (const float*)d_in[2];
  const float* W1   = (const float*)d_in[3];
  const float* att1 = (const float*)d_in[4];
  const float* b1   = (const float*)d_in[5];
  const float* W2   = (const float*)d_in[6];
  const float* b2   = (const float*)d_in[7];
  float* out = (float*)d_out;
  float* ws  = (float*)d_ws;

  float* xh     = ws + OFF_XH;
  float* s_j    = ws + OFF_SJ;
  float2* sird  = (float2*)(ws + OFF_SIRD);
  float* dinv   = ws + OFF_DINV;
  float* Binv   = ws + OFF_BINV;
  float* acc_e  = ws + OFF_ACCE;
  float* hbuf   = ws + OFF_H;
  float* xh2    = ws + OFF_XH2;
  float* acc_e2 = ws + OFF_ACCE2;
  int* rptr = (int*)(ws + OFF_RPTR);
  int* cptr = (int*)(ws + OFF_CPTR);
  int* bh_r = (int*)(ws + OFF_BHR);
  int* bh_c = (int*)(ws + OFF_BHC);
  int* bs_r = (int*)(ws + OFF_BSR);
  int* bs_c = (int*)(ws + OFF_BSC);
  int* bc_r = (int*)(ws + OFF_BCR);
  int* bc_c = (int*)(ws + OFF_BCC);
  int* csr_row_c = (int*)(ws + OFF_CSRRC);
  int* csr_col_r = (int*)(ws + OFF_CSRCR);
  int* tmp_r = (int*)(ws + OFF_XH);    // aliases xh (consumed before xh written)
  int* tmp_c = (int*)(ws + OFF_ACCE);  // aliases acc_e

  // --- CSR build (bucketed counting sort, both orderings) ---
  zero_small<<<1, 512, 0, stream>>>(bh_r, bh_c);
  bucket_hist<<<256, 256, 0, stream>>>(ei, bh_r, bh_c);
  bucket_scan<<<1, 512, 0, stream>>>(bh_r, bh_c, bs_r, bs_c, bc_r, bc_c);
  phaseA<<<(EE + EPB - 1) / EPB, 256, 0, stream>>>(ei, bc_r, bc_c, tmp_r, tmp_c);
  phaseB<<<2 * NB, 256, 0, stream>>>(tmp_r, tmp_c, bs_r, bs_c, hw,
                                     rptr, cptr, csr_row_c, csr_col_r, Binv);

  // --- Layer 1 ---
  gemm1_kernel<<<(NN + 63) / 64, 256, 0, stream>>>(x, W1, xh);
  attscore_kernel<<<(NN * NHEAD + 255) / 256, 256, 0, stream>>>(xh, att1, sird, s_j);
  den_csr<<<(NN * 64 + 255) / 256, 256, 0, stream>>>(rptr, csr_row_c, s_j, hw, sird, dinv);
  prop1_csr<<<(NN * 64 + 255) / 256, 256, 0, stream>>>(cptr, csr_col_r, xh, sird, s_j, Binv, acc_e);
  prop2_csr<<<(NN * 64 + 255) / 256, 256, 0, stream>>>(rptr, csr_row_c, acc_e, sird, s_j,
                                                       dinv, b1, hbuf);

  // --- Layer 2 ---
  gemm2_kernel<<<(NN * 8 + 255) / 256, 256, 0, stream>>>(hbuf, W2, xh2);
  prop3_csr<<<(NN * 8 + 255) / 256, 256, 0, stream>>>(cptr, csr_col_r, xh2, Binv, acc_e2);
  prop4_csr<<<(NN * 8 + 255) / 256, 256, 0, stream>>>(rptr, csr_row_c, acc_e2, dinv, b2, out);
}